// Round 6
// baseline (347.661 us; speedup 1.0000x reference)
//
#include <hip/hip_runtime.h>
#include <math.h>

#define NB 16
#define TT 800
#define FF 90
#define SS 128
#define LL 200
#define NEGV (-1e30f)

#define DNODES 16    // den nodes per utterance
#define DNDRX 50     // den frames per node (16*50 = 800)
#define PTROWS 25    // ptab rows resident (two-phase staging)
#define QNODES 32    // num nodes per utterance
#define QDRX 25      // num frames per node
#define BROW 26      // band diagonals (QDRX+1)
#define NEGH (-60000.0f)
#define EPAD 228     // padded num emission row (200 + 26 + slack)
#define LN2F 0.69314718055994531f
#define LOG2E 1.4426950408889634f

typedef __attribute__((ext_vector_type(8))) short short8;
typedef __attribute__((ext_vector_type(4))) float float4v;

static __device__ __forceinline__ unsigned short f2bf(float x) {
    union { float f; unsigned u; } v; v.f = x;
    unsigned r = (v.u + 0x7FFFu + ((v.u >> 16) & 1u)) >> 16;
    return (unsigned short)r;
}
// truncating bf16 pair pack in ONE VALU op (v_perm_b32), non-negative values
static __device__ __forceinline__ unsigned packperm(float a, float b) {
    return __builtin_amdgcn_perm(__float_as_uint(b), __float_as_uint(a),
                                 0x07060302u);
}
// XOR swizzle of 16B slots within a 64-word X row (validated r5)
static __device__ __forceinline__ int xsw(int row, int wrd) {
    return (wrd & 3) | ((((wrd >> 2) ^ (row & 7)) << 2));
}

// ======================= Prep: A fragments (r2-validated) ===================
__global__ __launch_bounds__(256) void mmi_prep(const float* __restrict__ trans,
                                                unsigned* __restrict__ AF) {
    const int idx = blockIdx.x * 256 + threadIdx.x;   // 0..2047
    const int l  = idx & 63, fk = idx >> 6;           // fk = mt*4+kc
    const int mt = fk >> 2, kc = fk & 3;
    const int q  = l >> 4,  m15 = l & 15;
    unsigned wv[4];
    #pragma unroll
    for (int j2 = 0; j2 < 4; ++j2) {
        const float a = __expf(trans[(kc * 32 + q * 8 + 2 * j2    ) * SS + mt * 16 + m15]);
        const float b = __expf(trans[(kc * 32 + q * 8 + 2 * j2 + 1) * SS + mt * 16 + m15]);
        wv[j2] = (unsigned)f2bf(a) | ((unsigned)f2bf(b) << 16);
    }
    *(uint4*)(AF + 4 * idx) = make_uint4(wv[0], wv[1], wv[2], wv[3]);
}

// ======================= Kernel A ===========================================
// 1024 blocks x 256 threads (4 waves), ~4 blocks/CU (16 waves = VGPR cap).
//   blockIdx <  512 -> HALF a den node (64 rows): node = bid>>1, half = bid&1.
//       Per-wave 16-row x 128-col running product, ZERO barriers in the
//       t-loop. Row-split is exact: rows evolve independently; Pout/scales8
//       layouts unchanged (half hb owns row-groups hb*4+w).
//   blockIdx >= 512 -> ONE num band node, column-parallel, triangle-cut.
__global__ __launch_bounds__(256, 4) void mmi_nodes(
    const float* __restrict__ x,
    const int*   __restrict__ sup,
    const float* __restrict__ trans,
    const int*   __restrict__ den_labels,
    const int*   __restrict__ num_labels,
    const unsigned* __restrict__ AF,    // 2048 x 16B prepped A fragments
    unsigned*    __restrict__ Pout,     // [NB*DNODES][8192] u32 (bf16 pairs)
    float*       __restrict__ scales8,  // [NB*DNODES][8] pow2 exps per row grp
    _Float16*    __restrict__ Bd)       // [NB*QNODES][201][BROW]
{
    __shared__ __align__(16) unsigned char SMEM[29440];
    const int tid = threadIdx.x;

    if (blockIdx.x < 2 * NB * DNODES) {
        // ---------------- den half-node (64 rows) ----------------
        const int node = blockIdx.x >> 1;
        const int hb   = blockIdx.x & 1;
        const int u  = node >> 4;
        const int nd = node & 15;
        const int t0 = nd * DNDRX;
        const int nf = sup[u * 3 + 2];
        unsigned* Pg = Pout + (size_t)node * 8192;

        if (t0 >= nf) {   // frozen node -> identity (this block's 64 rows)
            #pragma unroll
            for (int k2 = 0; k2 < 16; ++k2) {
                const int ww = tid + k2 * 256;        // 0..4095
                const int row = hb * 64 + (ww >> 6), colw = ww & 63;
                unsigned val = 0;
                if (row == 2 * colw)     val |= 0x3F80u;
                if (row == 2 * colw + 1) val |= 0x3F800000u;
                Pg[row * 64 + colw] = val;
            }
            if (tid < 4) scales8[node * 8 + hb * 4 + tid] = 0.0f;
            return;
        }

        const int w = tid >> 6, l = tid & 63;
        const int m15 = l & 15, q = l >> 4, h = m15 & 7;
        const int R0 = hb * 64 + w * 16;              // this wave's first row

        unsigned* Xs  = (unsigned*)SMEM;              // 4*16*64*4 = 16384 B
        float* ptab   = (float*)(SMEM + 16384);       // 25*128*4 = 12800 B

        // stage emissions phase A: frames t0..t0+24
        for (int idx = tid; idx < PTROWS * SS; idx += 256) {
            const int tt = idx >> 7, d = idx & 127;
            const int fr = min(t0 + tt, TT - 1);
            ptab[idx] = __expf(x[((size_t)u * TT + fr) * FF + den_labels[d]]);
        }
        __syncthreads();

        // per-wave init of own 16 rows: X0 = exp(T) * p0 (swizzled store)
        unsigned* Xw = Xs + w * (16 * 64);
        {
            const float p0 = ptab[2 * l], p1 = ptab[2 * l + 1];
            #pragma unroll
            for (int k2 = 0; k2 < 16; ++k2) {
                const int R = R0 + k2;
                const float2 t2 = ((const float2*)trans)[R * 64 + l];
                Xw[k2 * 64 + xsw(k2, l)] = packperm(__expf(t2.x) * p0,
                                                    __expf(t2.y) * p1);
            }
        }

        // A = exp(T)^T fragments: 32 coalesced 16B global loads
        short8 afrag[8][4];
        #pragma unroll
        for (int mt = 0; mt < 8; ++mt)
            #pragma unroll
            for (int kc = 0; kc < 4; ++kc)
                afrag[mt][kc] =
                    *(const short8*)(AF + ((mt * 4 + kc) * 64 + l) * 4);

        const unsigned short* XwH = (const unsigned short*)Xw;
        const int kmax = min(DNDRX, nf - t0);
        int eacc = 0;
        float redmax = 1.0f;

        int kbeg = 1;
        for (int ph = 0; ph < 2 && kbeg < kmax; ++ph) {
            const int kend = min(kmax, PTROWS * (ph + 1));
            const int kofs = ph * PTROWS;
            if (ph == 1) {
                __syncthreads();   // all waves done reading phase-A ptab
                for (int idx = tid; idx < PTROWS * SS; idx += 256) {
                    const int tt = PTROWS + (idx >> 7), d = idx & 127;
                    const int fr = min(t0 + tt, TT - 1);
                    ptab[idx] = __expf(x[((size_t)u * TT + fr) * FF +
                                         den_labels[d]]);
                }
                __syncthreads();
            }

            for (int k = kbeg; k < kend; ++k) {
                // pow2 renorm every 4th step, per-wave
                const bool dosc = ((k & 3) == 0);
                float sc = 1.0f;
                if (dosc) {
                    const float mm = fmaxf(redmax, 1e-37f);
                    const int e = (int)((__float_as_uint(mm) >> 23) & 255u);
                    sc = __uint_as_float((unsigned)(254 - e) << 23);
                    eacc += (e - 127);
                }

                short8 bf[4];
                #pragma unroll
                for (int kc = 0; kc < 4; ++kc)
                    bf[kc] = *(const short8*)(XwH + m15 * 128 +
                                              8 * (((kc << 2) | q) ^ h));

                float4v acc[8];
                #pragma unroll
                for (int mt = 0; mt < 8; ++mt) {
                    float4v z = {0.f, 0.f, 0.f, 0.f};
                    acc[mt] = z;
                }
                __builtin_amdgcn_s_setprio(1);
                #pragma unroll
                for (int kc = 0; kc < 4; ++kc)
                    #pragma unroll
                    for (int mt = 0; mt < 8; ++mt)
                        acc[mt] = __builtin_amdgcn_mfma_f32_16x16x32_bf16(
                            afrag[mt][kc], bf[kc], acc[mt], 0, 0, 0);
                __builtin_amdgcn_s_setprio(0);

                // emission (pre-scaled by sc) + optional vmax for next renorm
                const bool dmax = ((k & 3) == 3);
                float vmax = 0.0f;
                #pragma unroll
                for (int mt = 0; mt < 8; ++mt) {
                    float4 pc = *(const float4*)(ptab + (k - kofs) * SS +
                                                 mt * 16 + 4 * q);
                    if (dosc) { pc.x *= sc; pc.y *= sc; pc.z *= sc; pc.w *= sc; }
                    acc[mt][0] *= pc.x;
                    acc[mt][1] *= pc.y;
                    acc[mt][2] *= pc.z;
                    acc[mt][3] *= pc.w;
                    if (dmax)
                        vmax = fmaxf(vmax,
                            fmaxf(fmaxf(acc[mt][0], acc[mt][1]),
                                  fmaxf(acc[mt][2], acc[mt][3])));
                }
                if (dmax) {
                    #pragma unroll
                    for (int off = 32; off >= 1; off >>= 1)
                        vmax = fmaxf(vmax, __shfl_xor(vmax, off, 64));
                    redmax = vmax;
                }

                // in-place swizzled write; same-wave lgkmcnt ordering
                #pragma unroll
                for (int mt = 0; mt < 8; ++mt) {
                    uint2 pk;
                    pk.x = packperm(acc[mt][0], acc[mt][1]);
                    pk.y = packperm(acc[mt][2], acc[mt][3]);
                    *(uint2*)(Xw + m15 * 64 +
                              4 * (((mt << 1) | (q >> 1)) ^ h) + 2 * (q & 1)) = pk;
                }
            }
            kbeg = kend;
        }

        // epilogue: wave writes its own rows (un-swizzle on read)
        #pragma unroll
        for (int k2 = 0; k2 < 16; ++k2)
            Pg[(R0 + k2) * 64 + l] = Xw[k2 * 64 + xsw(k2, l)];
        if (l == 0) scales8[node * 8 + hb * 4 + w] = (float)eacc;
        return;
    }

    // ---------------- num band product: ONE node, column-parallel -----------
    {
        float* est = (float*)SMEM;                 // [25][EPAD] f32 = 22800 B

        const int slot = blockIdx.x - 2 * NB * DNODES;   // 0..511
        const int u    = slot >> 5;
        const int nd   = slot & 31;
        const int nf   = sup[u * 3 + 2];
        const int* nlu = num_labels + u * LL;

        for (int idx = tid; idx < QDRX * EPAD; idx += 256) {
            const int tt  = idx / EPAD;
            const int j   = idx - tt * EPAD;
            const int jj  = min(j, 199);
            const int fr  = min(nd * QDRX + tt, TT - 1);
            est[idx] = x[((size_t)u * TT + fr) * FF + nlu[jj]] * LOG2E;
        }
        __syncthreads();

        const int c  = tid;            // band source column (row r = c + d)
        const int t0 = nd * QDRX;
        const int kmaxg = min(QDRX, max(nf - t0, 0));

        // a[d] = B[c+d][d]: forward alpha of a unit mass started at row c.
        float a[BROW];
        a[0] = 0.0f;
        #pragma unroll
        for (int d = 1; d < BROW; ++d) a[d] = NEGV;

        const float* etc = est + (c - 1);
        for (int t = 0; t < kmaxg; ++t, etc += EPAD) {
            const int tc = t + 1;   // wave-uniform live-band bound
            #pragma unroll
            for (int d = BROW - 1; d >= 1; --d) {
                if (d <= tc) {
                    const float e  = etc[d];    // emission of row c+d
                    const float aa = a[d], bb = a[d - 1];
                    const float mx = fmaxf(aa, bb);
                    const float dd = fminf(aa, bb) - mx;
                    a[d] = e + mx +
                           __builtin_amdgcn_logf(
                               1.0f + __builtin_amdgcn_exp2f(dd));
                }
            }
            // d = 0: self-loop at row c (row 0 cannot persist)
            a[0] = (c == 0) ? NEGV : (etc[0] + a[0]);
        }

        if (c <= 200) {
            _Float16* Bg = Bd + (size_t)slot * 201 * BROW;
            #pragma unroll
            for (int d = 0; d < BROW; ++d) {
                const int r = c + d;
                if (r <= 200) Bg[r * BROW + d] = (_Float16)fmaxf(a[d], NEGH);
            }
            if (c < BROW - 1) {   // fill k > r triangle (unreachable transfers)
                for (int kk = c + 1; kk < BROW; ++kk)
                    Bg[c * BROW + kk] = (_Float16)NEGH;
            }
        }
    }
}

// ======================= Kernel B: chains + fused finalize (r5, validated) ==
__global__ __launch_bounds__(256) void mmi_chain(
    const unsigned short* __restrict__ Pmat,   // [16][DNODES][128*128] bf16
    const _Float16* __restrict__ Bd,           // [16][QNODES][201][BROW]
    const float* __restrict__ scales8,         // [16*DNODES][8]
    const int* __restrict__ num_lens,
    const int* __restrict__ sup,
    float* __restrict__ dsc,                   // [0..15] den, [16..31] num
    int*   __restrict__ ctr,                   // completion counter (1 int)
    float* __restrict__ out)
{
    __shared__ float sh_v[SS];
    __shared__ float sh_part[8 * SS];
    __shared__ float sh_red[2];
    __shared__ float ab[2][232];
    __shared__ int sfl;

    const int tid = threadIdx.x;

    if (blockIdx.x < NB) {
        const int u = blockIdx.x;
        const int gg = tid & 31, c = tid >> 5;
        const unsigned short* Pu = Pmat + (size_t)u * DNODES * 16384;

        if (tid < SS) sh_v[tid] = (tid == 0) ? 1.0f : 0.0f;
        int   e2acc = 0;
        float sscal = 0.0f;

        uint2 curm[16], nxt[16];
        #pragma unroll
        for (int j = 0; j < 16; ++j)
            curm[j] = *(const uint2*)(Pu + (16 * c + j) * SS + 4 * gg);
        __syncthreads();

        for (int i = 0; i < DNODES; ++i) {
            if (i + 1 < DNODES) {
                const unsigned short* Pn = Pu + (size_t)(i + 1) * 16384;
                #pragma unroll
                for (int j = 0; j < 16; ++j)
                    nxt[j] = *(const uint2*)(Pn + (16 * c + j) * SS + 4 * gg);
            }
            const float* s8 = scales8 + (size_t)(u * DNODES + i) * 8;
            float gmax = s8[0];
            #pragma unroll
            for (int g2 = 1; g2 < 8; ++g2) gmax = fmaxf(gmax, s8[g2]);
            const float fgr = __builtin_amdgcn_exp2f(s8[c] - gmax);
            sscal += gmax;

            const float4* av = (const float4*)(sh_v + 16 * c);
            float4 aa[4] = {av[0], av[1], av[2], av[3]};
            const float* as = (const float*)aa;
            float4 acc = make_float4(0.f, 0.f, 0.f, 0.f);
            #pragma unroll
            for (int j = 0; j < 16; ++j) {
                const float e0 = __uint_as_float(curm[j].x << 16);
                const float e1 = __uint_as_float(curm[j].x & 0xFFFF0000u);
                const float e2 = __uint_as_float(curm[j].y << 16);
                const float e3 = __uint_as_float(curm[j].y & 0xFFFF0000u);
                acc.x = fmaf(as[j], e0, acc.x);
                acc.y = fmaf(as[j], e1, acc.y);
                acc.z = fmaf(as[j], e2, acc.z);
                acc.w = fmaf(as[j], e3, acc.w);
            }
            acc.x *= fgr; acc.y *= fgr; acc.z *= fgr; acc.w *= fgr;
            *(float4*)(sh_part + c * SS + 4 * gg) = acc;
            __syncthreads();

            float v = 0.0f;
            if (tid < SS) {
                float y = 0.0f;
                #pragma unroll
                for (int cc = 0; cc < 8; ++cc) y += sh_part[cc * SS + tid];
                v = y;
                float m = v;
                #pragma unroll
                for (int off = 32; off >= 1; off >>= 1)
                    m = fmaxf(m, __shfl_xor(m, off, 64));
                if ((tid & 63) == 0) sh_red[tid >> 6] = m;
            }
            __syncthreads();
            if (tid < SS) {
                const float mm = fmaxf(fmaxf(sh_red[0], sh_red[1]), 1e-37f);
                const int e = (int)((__float_as_uint(mm) >> 23) & 255u);
                const float inv = __uint_as_float((unsigned)(254 - e) << 23);
                e2acc += (e - 127);
                sh_v[tid] = v * inv;
            }
            #pragma unroll
            for (int j = 0; j < 16; ++j) curm[j] = nxt[j];
            __syncthreads();
        }

        if (tid < SS) {
            float s = sh_v[tid];
            #pragma unroll
            for (int off = 32; off >= 1; off >>= 1)
                s += __shfl_xor(s, off, 64);
            if ((tid & 63) == 0) sh_red[tid >> 6] = s;
        }
        __syncthreads();
        if (tid == 0)
            atomicExch(&dsc[u], LN2F * ((float)e2acc + sscal) +
                                __logf(sh_red[0] + sh_red[1]));
    } else {
        // ---------------- num chain: band matvecs ----------------
        const int u = blockIdx.x - NB;
        const _Float16* Bu = Bd + (size_t)u * QNODES * 201 * BROW;
        const int r = tid;

        if (r < 232) { ab[0][r] = NEGV; ab[1][r] = NEGV; }
        float dv[BROW];
        if (r < 201) {
            #pragma unroll
            for (int k = 0; k < BROW; ++k) dv[k] = (float)Bu[r * BROW + k];
        }
        __syncthreads();
        if (r == 0) ab[0][QDRX] = 0.0f;    // alpha[0] = 0 (log2), offset QDRX
        __syncthreads();

        int cur = 0;
        for (int nd = 0; nd < QNODES; ++nd) {
            _Float16 nx[BROW];
            if (nd + 1 < QNODES && r < 201) {
                const _Float16* src = Bu + ((size_t)(nd + 1) * 201 + r) * BROW;
                #pragma unroll
                for (int k = 0; k < BROW; ++k) nx[k] = src[k];
            }
            float anew = NEGV;
            if (r < 201) {
                float tr[BROW];
                #pragma unroll
                for (int k = 0; k < BROW; ++k)
                    tr[k] = dv[k] + ab[cur][QDRX + r - k];
                float m = tr[0];
                #pragma unroll
                for (int k = 1; k < BROW; ++k) m = fmaxf(m, tr[k]);
                float s = 0.0f;
                #pragma unroll
                for (int k = 0; k < BROW; ++k)
                    s += __builtin_amdgcn_exp2f(tr[k] - m);
                anew = m + __builtin_amdgcn_logf(s);
            }
            if (r < 201) ab[cur ^ 1][QDRX + r] = anew;
            cur ^= 1;
            __syncthreads();
            if (r < 201) {
                #pragma unroll
                for (int k = 0; k < BROW; ++k) dv[k] = (float)nx[k];
            }
        }
        if (r == 0)
            atomicExch(&dsc[NB + u], ab[cur][QDRX + num_lens[u]] * LN2F);
    }

    // ---------------- fused finalize: last chain block ----------------
    __threadfence();
    if (tid == 0) sfl = (atomicAdd(ctr, 1) == 2 * NB - 1);
    __syncthreads();
    if (!sfl) return;
    __threadfence();
    if (tid < 64) {
        float tot_score = 0.0f, tot_frames = 0.0f, all_frames = 0.0f;
        if (tid < NB) {
            const float d = atomicAdd(&dsc[tid], 0.0f);       // coherent read
            const float n = atomicAdd(&dsc[NB + tid], 0.0f);
            const float tot = n - d;
            const int nf = sup[tid * 3 + 2];
            const bool fin = isfinite(tot) && (tot > 0.5f * NEGV);
            tot_score  = fin ? tot : 0.0f;
            tot_frames = fin ? (float)nf : 0.0f;
            all_frames = (float)nf;
        }
        #pragma unroll
        for (int off = 32; off >= 1; off >>= 1) {
            tot_score  += __shfl_xor(tot_score, off, 64);
            tot_frames += __shfl_xor(tot_frames, off, 64);
            all_frames += __shfl_xor(all_frames, off, 64);
        }
        if (tid == 0) {
            out[0] = tot_score;
            out[1] = tot_frames;
            out[2] = all_frames;
        }
    }
}

// ======================= Finalize (fallback path only) ======================
__global__ void mmi_finalize(const float* __restrict__ sc,
                             const int* __restrict__ sup,
                             float* __restrict__ out)
{
    const int tid = threadIdx.x;
    float tot_score = 0.0f, tot_frames = 0.0f, all_frames = 0.0f;
    if (tid < NB) {
        const float tot = sc[NB + tid] - sc[tid];
        const int nf = sup[tid * 3 + 2];
        const bool fin = isfinite(tot) && (tot > 0.5f * NEGV);
        tot_score  = fin ? tot : 0.0f;
        tot_frames = fin ? (float)nf : 0.0f;
        all_frames = (float)nf;
    }
    #pragma unroll
    for (int off = 32; off >= 1; off >>= 1) {
        tot_score  += __shfl_xor(tot_score, off, 64);
        tot_frames += __shfl_xor(tot_frames, off, 64);
        all_frames += __shfl_xor(all_frames, off, 64);
    }
    if (tid == 0) {
        out[0] = tot_score;
        out[1] = tot_frames;
        out[2] = all_frames;
    }
}

// ======================= Fallback (validated round-4 kernel) =================
#define XBF (16 * FF)
__global__ __launch_bounds__(256) void mmi_forward_fb(
    const float* __restrict__ x, const int* __restrict__ sup,
    const float* __restrict__ trans, const int* __restrict__ den_labels,
    const int* __restrict__ num_labels, const int* __restrict__ num_lens,
    float* __restrict__ ws)
{
    const int tid = threadIdx.x;
    if (blockIdx.x < NB) {
        __shared__ float sh_v[SS];
        __shared__ float sh_part[8 * SS];
        __shared__ float sh_red[4];
        __shared__ __align__(16) float xbuf[2][XBF];
        const int n = blockIdx.x, nf = sup[n * 3 + 2];
        const int g = tid & 31, c = tid >> 5;
        float4 e[16];
        #pragma unroll
        for (int j = 0; j < 16; ++j) {
            const float4 t4 = *(const float4*)(trans + (size_t)(16 * c + j) * SS + 4 * g);
            e[j] = make_float4(__expf(t4.x), __expf(t4.y), __expf(t4.z), __expf(t4.w));
        }
        const int lab = (tid < SS) ? den_labels[tid & (SS - 1)] : 0;
        const float* xb = x + (size_t)n * TT * FF;
        {
            const float4* s0 = (const float4*)xb;
            float4 p0 = s0[tid]; float4 p1; if (tid < 104) p1 = s0[256 + tid];
            float4* d0 = (float4*)xbuf[0];
            d0[tid] = p0; if (tid < 104) d0[256 + tid] = p1;
        }
        if (tid < SS) sh_v[tid] = (tid == 0) ? 1.0f : 0.0f;
        float logM = 0.0f, v = 0.0f, pe = 0.0f;
        float4 pf0, pf1;
        __syncthreads();
        for (int t = 0; t < nf; ++t) {
            const int b = t >> 4;
            if (tid < SS) pe = __expf(xbuf[b & 1][(t & 15) * FF + lab]);
            float4 aa[4];
            { const float4* av = (const float4*)(sh_v + 16 * c);
              aa[0] = av[0]; aa[1] = av[1]; aa[2] = av[2]; aa[3] = av[3]; }
            const float* as = (const float*)aa;
            float4 acc = make_float4(0.f, 0.f, 0.f, 0.f);
            #pragma unroll
            for (int j = 0; j < 16; ++j) {
                acc.x = fmaf(as[j], e[j].x, acc.x); acc.y = fmaf(as[j], e[j].y, acc.y);
                acc.z = fmaf(as[j], e[j].z, acc.z); acc.w = fmaf(as[j], e[j].w, acc.w);
            }
            *(float4*)(sh_part + c * SS + 4 * g) = acc;
            if ((t & 15) == 8) {
                const int tn = (b + 1) * 16;
                if (tn < nf) {
                    const float4* s = (const float4*)(xb + (size_t)tn * FF);
                    pf0 = s[tid]; if (tid < 104) pf1 = s[256 + tid];
                }
            }
            __syncthreads();
            const bool rs = ((t & 15) == 15);
            if (tid < SS) {
                float y = 0.0f;
                #pragma unroll
                for (int cc = 0; cc < 8; ++cc) y += sh_part[cc * SS + tid];
                v = y * pe;
                if (rs) {
                    float m = v;
                    #pragma unroll
                    for (int off = 32; off >= 1; off >>= 1)
                        m = fmaxf(m, __shfl_xor(m, off, 64));
                    if ((tid & 63) == 0) sh_red[tid >> 6] = m;
                }
            }
            if (rs) {
                const int tn = (b + 1) * 16;
                if (tn < nf) {
                    float4* dst = (float4*)xbuf[(b + 1) & 1];
                    dst[tid] = pf0; if (tid < 104) dst[256 + tid] = pf1;
                }
                __syncthreads();
                if (tid < SS) {
                    float mm = fmaxf(fmaxf(sh_red[0], sh_red[1]), 1e-37f);
                    v *= (1.0f / mm); logM += __logf(mm);
                }
            }
            if (tid < SS) sh_v[tid] = v;
            __syncthreads();
        }
        if (tid < SS) {
            float ssum = v;
            #pragma unroll
            for (int off = 32; off >= 1; off >>= 1) ssum += __shfl_xor(ssum, off, 64);
            if ((tid & 63) == 0) sh_red[2 + (tid >> 6)] = ssum;
        }
        __syncthreads();
        if (tid == 0) ws[n] = logM + __logf(sh_red[2] + sh_red[3]);
    } else {
        const int w = tid >> 6, l = tid & 63;
        const int n = (blockIdx.x - NB) * 4 + w;
        const int nf = sup[n * 3 + 2];
        const float* xb = x + (size_t)n * TT * FF;
        const int* nl = num_labels + n * LL;
        int li[4];
        #pragma unroll
        for (int k = 0; k < 4; ++k) li[k] = nl[min(4 * l + k, LL - 1)];
        float a4[4] = {NEGV, NEGV, NEGV, NEGV};
        float ea[4], eb[4];
        #pragma unroll
        for (int k = 0; k < 4; ++k) ea[k] = xb[li[k]];
        { const float* xr = xb + (size_t)min(1, nf - 1) * FF;
          #pragma unroll
          for (int k = 0; k < 4; ++k) eb[k] = xr[li[k]]; }
        auto step = [&](float (&ee)[4], int t) {
            float left = __shfl_up(a4[3], 1, 64);
            if (l == 0) left = (t == 0) ? 0.0f : NEGV;
            float prev = left;
            #pragma unroll
            for (int k = 0; k < 4; ++k) {
                const float a = a4[k], b = prev;
                const float mx = fmaxf(a, b), mn = fminf(a, b);
                const float nv = mx + __logf(1.0f + __expf(mn - mx)) + ee[k];
                prev = a4[k]; a4[k] = nv;
            }
            const int t2 = min(t + 2, nf - 1);
            const float* xr = xb + (size_t)t2 * FF;
            #pragma unroll
            for (int k = 0; k < 4; ++k) ee[k] = xr[li[k]];
        };
        int t = 0;
        while (t < nf) { step(ea, t); ++t; if (t >= nf) break; step(eb, t); ++t; }
        const int idx = num_lens[n] - 1;
        if ((idx >> 2) == l) {
            const int kk = idx & 3;
            float vv = (kk == 0) ? a4[0] : (kk == 1) ? a4[1] : (kk == 2) ? a4[2] : a4[3];
            ws[NB + n] = vv;
        }
    }
}

extern "C" void kernel_launch(void* const* d_in, const int* in_sizes, int n_in,
                              void* d_out, int out_size, void* d_ws, size_t ws_size,
                              hipStream_t stream) {
    const float* x          = (const float*)d_in[0];
    const int*   sup        = (const int*)d_in[1];
    const float* trans      = (const float*)d_in[2];
    const int*   den_labels = (const int*)d_in[3];
    const int*   num_labels = (const int*)d_in[4];
    const int*   num_lens   = (const int*)d_in[5];
    float* out = (float*)d_out;

    const size_t PBYTES = (size_t)NB * DNODES * 32768;              // 8,388,608
    const size_t BBYTES = (size_t)NB * QNODES * 201 * BROW * 2;     // 5,351,424
    const size_t SCB    = (size_t)NB * DNODES * 8 * sizeof(float);  // 32,768
    const size_t SOFF   = PBYTES + BBYTES;
    const size_t DOFF   = SOFF + SCB;              // dsc (64 floats)
    const size_t COFF   = DOFF + 256;              // counter
    const size_t AOFF   = COFF + 256;              // AF fragments
    const size_t NEEDED = AOFF + 2048 * 16;

    if (ws_size >= NEEDED) {
        unsigned*  Pout    = (unsigned*)d_ws;
        _Float16*  Bd      = (_Float16*)((char*)d_ws + PBYTES);
        float*     scales8 = (float*)((char*)d_ws + SOFF);
        float*     dsc     = (float*)((char*)d_ws + DOFF);
        int*       ctr     = (int*)((char*)d_ws + COFF);
        unsigned*  AF      = (unsigned*)((char*)d_ws + AOFF);
        hipMemsetAsync(ctr, 0, 64, stream);
        mmi_prep<<<dim3(8), dim3(256), 0, stream>>>(trans, AF);
        mmi_nodes<<<dim3(1024), dim3(256), 0, stream>>>(
            x, sup, trans, den_labels, num_labels, AF, Pout, scales8, Bd);
        mmi_chain<<<dim3(2 * NB), dim3(256), 0, stream>>>(
            (const unsigned short*)d_ws, Bd, scales8, num_lens, sup,
            dsc, ctr, out);
    } else {
        float* ws = (float*)d_ws;
        mmi_forward_fb<<<dim3(20), dim3(256), 0, stream>>>(
            x, sup, trans, den_labels, num_labels, num_lens, ws);
        mmi_finalize<<<dim3(1), dim3(64), 0, stream>>>(ws, sup, out);
    }
}

// Round 7
// 197.184 us; speedup vs baseline: 1.7631x; 1.7631x over previous
//
#include <hip/hip_runtime.h>
#include <math.h>

#define NB 16
#define TT 800
#define FF 90
#define SS 128
#define LL 200
#define NEGV (-1e30f)

#define DNODES 16    // den nodes per utterance
#define DNDRX 50     // den frames per node (16*50 = 800)
#define QNODES 32    // num nodes per utterance
#define QDRX 25      // num frames per node
#define BROW 26      // band diagonals (QDRX+1)
#define BST 28       // Bd row stride in halves (56B, 8B-aligned)
#define NEGH (-60000.0f)
#define EPAD 228     // padded num emission row (200 + 26 + slack)
#define LN2F 0.69314718055994531f
#define LOG2E 1.4426950408889634f

typedef __attribute__((ext_vector_type(8))) short short8;
typedef __attribute__((ext_vector_type(4))) float float4v;
typedef _Float16 h4 __attribute__((ext_vector_type(4)));   // 8B vector of halves

static __device__ __forceinline__ unsigned short f2bf(float x) {
    union { float f; unsigned u; } v; v.f = x;
    unsigned r = (v.u + 0x7FFFu + ((v.u >> 16) & 1u)) >> 16;
    return (unsigned short)r;
}
// truncating bf16 pair pack in ONE VALU op (v_perm_b32), non-negative values
static __device__ __forceinline__ unsigned packperm(float a, float b) {
    return __builtin_amdgcn_perm(__float_as_uint(b), __float_as_uint(a),
                                 0x07060302u);
}
// XOR swizzle of 16B slots within a 64-word X row (validated r5)
static __device__ __forceinline__ int xsw(int row, int wrd) {
    return (wrd & 3) | ((((wrd >> 2) ^ (row & 7)) << 2));
}

// ======================= Kernel A (r5-validated, 105us, absmax 0) ===========
// 512 blocks x 512 threads (8 waves). Dens (blocks 0..255) dispatch first.
//   den block: per-wave 16-row x 128-col running product, ZERO barriers in
//       the t-loop. X rows XOR-swizzled. A-fragments staged in-block.
//   num block: TWO band nodes, column-parallel, triangle-cut inner loop.
__global__ __launch_bounds__(512, 2) void mmi_nodes(
    const float* __restrict__ x,
    const int*   __restrict__ sup,
    const float* __restrict__ trans,
    const int*   __restrict__ den_labels,
    const int*   __restrict__ num_labels,
    unsigned*    __restrict__ Pout,     // [NB*DNODES][8192] u32 (bf16 pairs)
    float*       __restrict__ scales8,  // [NB*DNODES][8] pow2 exps per row grp
    _Float16*    __restrict__ Bd)       // [NB*QNODES][201][BST]
{
    __shared__ __align__(16) unsigned char SMEM[58368];
    const int tid = threadIdx.x;

    if (blockIdx.x < NB * DNODES) {
        // ---------------- den node product ----------------
        const int bid = blockIdx.x;
        const int u  = bid >> 4;
        const int nd = bid & 15;
        const int t0 = nd * DNDRX;
        const int nf = sup[u * 3 + 2];
        unsigned* Pg = Pout + (size_t)bid * 8192;

        if (t0 >= nf) {   // frozen node -> identity
            #pragma unroll
            for (int k2 = 0; k2 < 16; ++k2) {
                const int ww = tid + k2 * 512;
                const int row = ww >> 6, colw = ww & 63;
                unsigned val = 0;
                if (row == 2 * colw)     val |= 0x3F80u;
                if (row == 2 * colw + 1) val |= 0x3F800000u;
                Pg[ww] = val;
            }
            if (tid < 8) scales8[bid * 8 + tid] = 0.0f;
            return;
        }

        const int w = tid >> 6, l = tid & 63;
        const int m15 = l & 15, q = l >> 4, h = m15 & 7;

        // ---- stage A = exp(T)^T fragments through LDS (one-shot) ----
        unsigned* AFs = (unsigned*)SMEM;              // 8192 u32 = 32 KB
        #pragma unroll
        for (int i = 0; i < 16; ++i) {
            const int wi = tid + i * 512;             // 0..8191
            const int f  = wi >> 2, j2 = wi & 3;
            const int fl = f & 63, kc = (f >> 6) & 3, mt = f >> 8;
            const int col = mt * 16 + (fl & 15);
            const int krow = kc * 32 + (fl >> 4) * 8 + 2 * j2;
            const float a = __expf(trans[(krow    ) * SS + col]);
            const float b = __expf(trans[(krow + 1) * SS + col]);
            AFs[wi] = (unsigned)f2bf(a) | ((unsigned)f2bf(b) << 16);
        }
        __syncthreads();
        short8 afrag[8][4];
        #pragma unroll
        for (int mt = 0; mt < 8; ++mt)
            #pragma unroll
            for (int kc = 0; kc < 4; ++kc)
                afrag[mt][kc] =
                    *(const short8*)(AFs + ((mt * 4 + kc) * 64 + l) * 4);
        __syncthreads();   // WAR: AFs region becomes Xs below

        unsigned* Xs  = (unsigned*)SMEM;              // 8*16*64*4 = 32768 B
        float* ptab   = (float*)(SMEM + 32768);       // 50*128*4 = 25600 B

        for (int idx = tid; idx < DNDRX * SS; idx += 512) {
            const int tt = idx >> 7, d = idx & 127;
            const int fr = min(t0 + tt, TT - 1);
            ptab[idx] = __expf(x[((size_t)u * TT + fr) * FF + den_labels[d]]);
        }
        __syncthreads();   // ptab visible; last block-wide barrier

        // per-wave init of own 16 rows: X0 = exp(T) * p0 (swizzled store)
        unsigned* Xw = Xs + w * (16 * 64);
        {
            const float p0 = ptab[2 * l], p1 = ptab[2 * l + 1];
            #pragma unroll
            for (int k2 = 0; k2 < 16; ++k2) {
                const int R = w * 16 + k2;
                const float2 t2 = ((const float2*)trans)[R * 64 + l];
                Xw[k2 * 64 + xsw(k2, l)] = packperm(__expf(t2.x) * p0,
                                                    __expf(t2.y) * p1);
            }
        }

        const unsigned short* XwH = (const unsigned short*)Xw;
        const int kmax = min(DNDRX, nf - t0);
        int eacc = 0;
        float redmax = 1.0f;

        for (int k = 1; k < kmax; ++k) {
            // pow2 renorm every 4th step, per-wave
            const bool dosc = ((k & 3) == 0);
            float sc = 1.0f;
            if (dosc) {
                const float mm = fmaxf(redmax, 1e-37f);
                const int e = (int)((__float_as_uint(mm) >> 23) & 255u);
                sc = __uint_as_float((unsigned)(254 - e) << 23);
                eacc += (e - 127);
            }

            short8 bf[4];
            #pragma unroll
            for (int kc = 0; kc < 4; ++kc)
                bf[kc] = *(const short8*)(XwH + m15 * 128 +
                                          8 * (((kc << 2) | q) ^ h));

            float4v acc[8];
            #pragma unroll
            for (int mt = 0; mt < 8; ++mt) {
                float4v z = {0.f, 0.f, 0.f, 0.f};
                acc[mt] = z;
            }
            __builtin_amdgcn_s_setprio(1);
            #pragma unroll
            for (int kc = 0; kc < 4; ++kc)
                #pragma unroll
                for (int mt = 0; mt < 8; ++mt)
                    acc[mt] = __builtin_amdgcn_mfma_f32_16x16x32_bf16(
                        afrag[mt][kc], bf[kc], acc[mt], 0, 0, 0);
            __builtin_amdgcn_s_setprio(0);

            // emission (pre-scaled by sc) + optional vmax for next renorm
            const bool dmax = ((k & 3) == 3);
            float vmax = 0.0f;
            #pragma unroll
            for (int mt = 0; mt < 8; ++mt) {
                float4 pc = *(const float4*)(ptab + k * SS + mt * 16 + 4 * q);
                if (dosc) { pc.x *= sc; pc.y *= sc; pc.z *= sc; pc.w *= sc; }
                acc[mt][0] *= pc.x;
                acc[mt][1] *= pc.y;
                acc[mt][2] *= pc.z;
                acc[mt][3] *= pc.w;
                if (dmax)
                    vmax = fmaxf(vmax,
                        fmaxf(fmaxf(acc[mt][0], acc[mt][1]),
                              fmaxf(acc[mt][2], acc[mt][3])));
            }
            if (dmax) {
                #pragma unroll
                for (int off = 32; off >= 1; off >>= 1)
                    vmax = fmaxf(vmax, __shfl_xor(vmax, off, 64));
                redmax = vmax;
            }

            // in-place swizzled write; same-wave lgkmcnt ordering, no barrier
            #pragma unroll
            for (int mt = 0; mt < 8; ++mt) {
                uint2 pk;
                pk.x = packperm(acc[mt][0], acc[mt][1]);
                pk.y = packperm(acc[mt][2], acc[mt][3]);
                *(uint2*)(Xw + m15 * 64 +
                          4 * (((mt << 1) | (q >> 1)) ^ h) + 2 * (q & 1)) = pk;
            }
        }

        // epilogue: wave writes its own rows (un-swizzle on read)
        #pragma unroll
        for (int k2 = 0; k2 < 16; ++k2)
            Pg[(w * 16 + k2) * 64 + l] = Xw[k2 * 64 + xsw(k2, l)];
        if (l == 0) scales8[bid * 8 + w] = (float)eacc;
        return;
    }

    // ---------------- num band products: 2 nodes/block, column-parallel -----
    {
        float* est = (float*)(SMEM + 16);          // [2][25][EPAD] f32

        const int qb    = blockIdx.x - NB * DNODES;
        const int slot0 = qb * 2;
        const int u     = slot0 / QNODES;          // both nodes in same utt
        const int nd0   = slot0 - u * QNODES;
        const int nf    = sup[u * 3 + 2];
        const int* nlu  = num_labels + u * LL;

        for (int idx = tid; idx < 2 * QDRX * EPAD; idx += 512) {
            const int g   = idx / (QDRX * EPAD);
            const int rem = idx - g * (QDRX * EPAD);
            const int tt  = rem / EPAD;
            const int j   = rem - tt * EPAD;
            const int jj  = min(j, 199);
            const int fr  = min((nd0 + g) * QDRX + tt, TT - 1);
            est[idx] = x[((size_t)u * TT + fr) * FF + nlu[jj]] * LOG2E;
        }
        __syncthreads();

        const int g  = tid >> 8;       // node half 0/1
        const int c  = tid & 255;      // band source column (row r = c + d)
        const int nd = nd0 + g;
        const int t0 = nd * QDRX;
        const int kmaxg = min(QDRX, max(nf - t0, 0));
        const float* eg = est + g * (QDRX * EPAD);

        // a[d] = B[c+d][d]: forward alpha of a unit mass started at row c.
        float a[BROW];
        a[0] = 0.0f;
        #pragma unroll
        for (int d = 1; d < BROW; ++d) a[d] = NEGV;

        const float* etc = eg + (c - 1);
        for (int t = 0; t < kmaxg; ++t, etc += EPAD) {
            const int tc = t + 1;   // wave-uniform live-band bound
            #pragma unroll
            for (int d = BROW - 1; d >= 1; --d) {
                if (d <= tc) {
                    const float e  = etc[d];    // emission of row c+d
                    const float aa = a[d], bb = a[d - 1];
                    const float mx = fmaxf(aa, bb);
                    const float dd = fminf(aa, bb) - mx;
                    a[d] = e + mx +
                           __builtin_amdgcn_logf(
                               1.0f + __builtin_amdgcn_exp2f(dd));
                }
            }
            // d = 0: self-loop at row c (row 0 cannot persist)
            a[0] = (c == 0) ? NEGV : (etc[0] + a[0]);
        }

        if (c <= 200) {
            _Float16* Bg = Bd + (size_t)(slot0 + g) * 201 * BST;
            #pragma unroll
            for (int d = 0; d < BROW; ++d) {
                const int r = c + d;
                if (r <= 200) Bg[r * BST + d] = (_Float16)fmaxf(a[d], NEGH);
            }
            if (c < BROW - 1) {   // fill k > r triangle (unreachable transfers)
                for (int kk = c + 1; kk < BROW; ++kk)
                    Bg[c * BST + kk] = (_Float16)NEGH;
            }
        }
    }
}

// ======================= Kernel B: chains + fused finalize ==================
// 512 threads/block now: den chain uses row-groups of 8 (2x MLP) + depth-2
// prefetch; num chain uses 8B-aligned vector loads + depth-2 prefetch.
__global__ __launch_bounds__(512) void mmi_chain(
    const unsigned short* __restrict__ Pmat,   // [16][DNODES][128*128] bf16
    const _Float16* __restrict__ Bd,           // [16][QNODES][201][BST]
    const float* __restrict__ scales8,         // [16*DNODES][8]
    const int* __restrict__ num_lens,
    const int* __restrict__ sup,
    float* __restrict__ dsc,                   // [0..15] den, [16..31] num
    int*   __restrict__ ctr,                   // completion counter (1 int)
    float* __restrict__ out)
{
    __shared__ float sh_v[SS];
    __shared__ float sh_part[16 * SS];
    __shared__ float sh_red[2];
    __shared__ float ab[2][232];
    __shared__ int sfl;

    const int tid = threadIdx.x;

    if (blockIdx.x < NB) {
        const int u = blockIdx.x;
        const int gg = tid & 31, c = tid >> 5;        // c 0..15, rows 8c..8c+7
        const unsigned short* Pu = Pmat + (size_t)u * DNODES * 16384;

        if (tid < SS) sh_v[tid] = (tid == 0) ? 1.0f : 0.0f;
        int   e2acc = 0;
        float sscal = 0.0f;

        uint2 cur[8], nx1[8], nx2[8];
        #pragma unroll
        for (int j = 0; j < 8; ++j)
            cur[j] = *(const uint2*)(Pu + (8 * c + j) * SS + 4 * gg);
        #pragma unroll
        for (int j = 0; j < 8; ++j)
            nx1[j] = *(const uint2*)(Pu + 16384 + (8 * c + j) * SS + 4 * gg);
        __syncthreads();

        for (int i = 0; i < DNODES; ++i) {
            if (i + 2 < DNODES) {
                const unsigned short* Pn = Pu + (size_t)(i + 2) * 16384;
                #pragma unroll
                for (int j = 0; j < 8; ++j)
                    nx2[j] = *(const uint2*)(Pn + (8 * c + j) * SS + 4 * gg);
            }
            // per-row-group pow2 scales of this node (group of 16 rows = c>>1)
            const float* s8 = scales8 + (size_t)(u * DNODES + i) * 8;
            float gmax = s8[0];
            #pragma unroll
            for (int g2 = 1; g2 < 8; ++g2) gmax = fmaxf(gmax, s8[g2]);
            const float fgr = __builtin_amdgcn_exp2f(s8[c >> 1] - gmax);
            sscal += gmax;

            const float4* av = (const float4*)(sh_v + 8 * c);
            float4 aa[2] = {av[0], av[1]};
            const float* as = (const float*)aa;
            float4 acc = make_float4(0.f, 0.f, 0.f, 0.f);
            #pragma unroll
            for (int j = 0; j < 8; ++j) {
                const float e0 = __uint_as_float(cur[j].x << 16);
                const float e1 = __uint_as_float(cur[j].x & 0xFFFF0000u);
                const float e2 = __uint_as_float(cur[j].y << 16);
                const float e3 = __uint_as_float(cur[j].y & 0xFFFF0000u);
                acc.x = fmaf(as[j], e0, acc.x);
                acc.y = fmaf(as[j], e1, acc.y);
                acc.z = fmaf(as[j], e2, acc.z);
                acc.w = fmaf(as[j], e3, acc.w);
            }
            acc.x *= fgr; acc.y *= fgr; acc.z *= fgr; acc.w *= fgr;
            *(float4*)(sh_part + c * SS + 4 * gg) = acc;
            __syncthreads();

            float v = 0.0f;
            if (tid < SS) {
                float y = 0.0f;
                #pragma unroll
                for (int cc = 0; cc < 16; ++cc) y += sh_part[cc * SS + tid];
                v = y;
                float m = v;
                #pragma unroll
                for (int off = 32; off >= 1; off >>= 1)
                    m = fmaxf(m, __shfl_xor(m, off, 64));
                if ((tid & 63) == 0) sh_red[tid >> 6] = m;
            }
            __syncthreads();
            if (tid < SS) {
                const float mm = fmaxf(fmaxf(sh_red[0], sh_red[1]), 1e-37f);
                const int e = (int)((__float_as_uint(mm) >> 23) & 255u);
                const float inv = __uint_as_float((unsigned)(254 - e) << 23);
                e2acc += (e - 127);
                sh_v[tid] = v * inv;
            }
            #pragma unroll
            for (int j = 0; j < 8; ++j) { cur[j] = nx1[j]; nx1[j] = nx2[j]; }
            __syncthreads();
        }

        if (tid < SS) {
            float s = sh_v[tid];
            #pragma unroll
            for (int off = 32; off >= 1; off >>= 1)
                s += __shfl_xor(s, off, 64);
            if ((tid & 63) == 0) sh_red[tid >> 6] = s;
        }
        __syncthreads();
        if (tid == 0)
            atomicExch(&dsc[u], LN2F * ((float)e2acc + sscal) +
                                __logf(sh_red[0] + sh_red[1]));
    } else {
        // ---------------- num chain: band matvecs ----------------
        const int u = blockIdx.x - NB;
        const _Float16* Bu = Bd + (size_t)u * QNODES * 201 * BST;
        const int r = tid;
        const bool act = (r < 201);

        if (r < 232) { ab[0][r] = NEGV; ab[1][r] = NEGV; }
        h4 nx1[7], nx2[7];
        float dv[BROW];
        if (act) {
            const h4* s0 = (const h4*)(Bu + (size_t)r * BST);
            #pragma unroll
            for (int t7 = 0; t7 < 7; ++t7) nx1[t7] = s0[t7];
            #pragma unroll
            for (int k = 0; k < BROW; ++k) dv[k] = (float)nx1[k >> 2][k & 3];
            const h4* s1 = (const h4*)(Bu + ((size_t)201 + r) * BST);
            #pragma unroll
            for (int t7 = 0; t7 < 7; ++t7) nx1[t7] = s1[t7];
        }
        __syncthreads();
        if (r == 0) ab[0][QDRX] = 0.0f;    // alpha[0] = 0 (log2), offset QDRX
        __syncthreads();

        int cur = 0;
        for (int nd = 0; nd < QNODES; ++nd) {
            if (nd + 2 < QNODES && act) {
                const h4* src = (const h4*)(Bu + ((size_t)(nd + 2) * 201 + r) * BST);
                #pragma unroll
                for (int t7 = 0; t7 < 7; ++t7) nx2[t7] = src[t7];
            }
            float anew = NEGV;
            if (act) {
                float tr[BROW];
                #pragma unroll
                for (int k = 0; k < BROW; ++k)
                    tr[k] = dv[k] + ab[cur][QDRX + r - k];
                float m = tr[0];
                #pragma unroll
                for (int k = 1; k < BROW; ++k) m = fmaxf(m, tr[k]);
                float s = 0.0f;
                #pragma unroll
                for (int k = 0; k < BROW; ++k)
                    s += __builtin_amdgcn_exp2f(tr[k] - m);
                anew = m + __builtin_amdgcn_logf(s);
            }
            if (act) ab[cur ^ 1][QDRX + r] = anew;
            cur ^= 1;
            __syncthreads();
            if (act) {
                #pragma unroll
                for (int k = 0; k < BROW; ++k) dv[k] = (float)nx1[k >> 2][k & 3];
                #pragma unroll
                for (int t7 = 0; t7 < 7; ++t7) nx1[t7] = nx2[t7];
            }
        }
        if (r == 0)
            atomicExch(&dsc[NB + u], ab[cur][QDRX + num_lens[u]] * LN2F);
    }

    // ---------------- fused finalize: last chain block ----------------
    __threadfence();
    if (tid == 0) sfl = (atomicAdd(ctr, 1) == 2 * NB - 1);
    __syncthreads();
    if (!sfl) return;
    __threadfence();
    if (tid < 64) {
        float tot_score = 0.0f, tot_frames = 0.0f, all_frames = 0.0f;
        if (tid < NB) {
            const float d = atomicAdd(&dsc[tid], 0.0f);       // coherent read
            const float n = atomicAdd(&dsc[NB + tid], 0.0f);
            const float tot = n - d;
            const int nf = sup[tid * 3 + 2];
            const bool fin = isfinite(tot) && (tot > 0.5f * NEGV);
            tot_score  = fin ? tot : 0.0f;
            tot_frames = fin ? (float)nf : 0.0f;
            all_frames = (float)nf;
        }
        #pragma unroll
        for (int off = 32; off >= 1; off >>= 1) {
            tot_score  += __shfl_xor(tot_score, off, 64);
            tot_frames += __shfl_xor(tot_frames, off, 64);
            all_frames += __shfl_xor(all_frames, off, 64);
        }
        if (tid == 0) {
            out[0] = tot_score;
            out[1] = tot_frames;
            out[2] = all_frames;
        }
    }
}

// ======================= Finalize (fallback path only) ======================
__global__ void mmi_finalize(const float* __restrict__ sc,
                             const int* __restrict__ sup,
                             float* __restrict__ out)
{
    const int tid = threadIdx.x;
    float tot_score = 0.0f, tot_frames = 0.0f, all_frames = 0.0f;
    if (tid < NB) {
        const float tot = sc[NB + tid] - sc[tid];
        const int nf = sup[tid * 3 + 2];
        const bool fin = isfinite(tot) && (tot > 0.5f * NEGV);
        tot_score  = fin ? tot : 0.0f;
        tot_frames = fin ? (float)nf : 0.0f;
        all_frames = (float)nf;
    }
    #pragma unroll
    for (int off = 32; off >= 1; off >>= 1) {
        tot_score  += __shfl_xor(tot_score, off, 64);
        tot_frames += __shfl_xor(tot_frames, off, 64);
        all_frames += __shfl_xor(all_frames, off, 64);
    }
    if (tid == 0) {
        out[0] = tot_score;
        out[1] = tot_frames;
        out[2] = all_frames;
    }
}

// ======================= Fallback (validated round-4 kernel) =================
#define XBF (16 * FF)
__global__ __launch_bounds__(256) void mmi_forward_fb(
    const float* __restrict__ x, const int* __restrict__ sup,
    const float* __restrict__ trans, const int* __restrict__ den_labels,
    const int* __restrict__ num_labels, const int* __restrict__ num_lens,
    float* __restrict__ ws)
{
    const int tid = threadIdx.x;
    if (blockIdx.x < NB) {
        __shared__ float sh_v[SS];
        __shared__ float sh_part[8 * SS];
        __shared__ float sh_red[4];
        __shared__ __align__(16) float xbuf[2][XBF];
        const int n = blockIdx.x, nf = sup[n * 3 + 2];
        const int g = tid & 31, c = tid >> 5;
        float4 e[16];
        #pragma unroll
        for (int j = 0; j < 16; ++j) {
            const float4 t4 = *(const float4*)(trans + (size_t)(16 * c + j) * SS + 4 * g);
            e[j] = make_float4(__expf(t4.x), __expf(t4.y), __expf(t4.z), __expf(t4.w));
        }
        const int lab = (tid < SS) ? den_labels[tid & (SS - 1)] : 0;
        const float* xb = x + (size_t)n * TT * FF;
        {
            const float4* s0 = (const float4*)xb;
            float4 p0 = s0[tid]; float4 p1; if (tid < 104) p1 = s0[256 + tid];
            float4* d0 = (float4*)xbuf[0];
            d0[tid] = p0; if (tid < 104) d0[256 + tid] = p1;
        }
        if (tid < SS) sh_v[tid] = (tid == 0) ? 1.0f : 0.0f;
        float logM = 0.0f, v = 0.0f, pe = 0.0f;
        float4 pf0, pf1;
        __syncthreads();
        for (int t = 0; t < nf; ++t) {
            const int b = t >> 4;
            if (tid < SS) pe = __expf(xbuf[b & 1][(t & 15) * FF + lab]);
            float4 aa[4];
            { const float4* av = (const float4*)(sh_v + 16 * c);
              aa[0] = av[0]; aa[1] = av[1]; aa[2] = av[2]; aa[3] = av[3]; }
            const float* as = (const float*)aa;
            float4 acc = make_float4(0.f, 0.f, 0.f, 0.f);
            #pragma unroll
            for (int j = 0; j < 16; ++j) {
                acc.x = fmaf(as[j], e[j].x, acc.x); acc.y = fmaf(as[j], e[j].y, acc.y);
                acc.z = fmaf(as[j], e[j].z, acc.z); acc.w = fmaf(as[j], e[j].w, acc.w);
            }
            *(float4*)(sh_part + c * SS + 4 * g) = acc;
            if ((t & 15) == 8) {
                const int tn = (b + 1) * 16;
                if (tn < nf) {
                    const float4* s = (const float4*)(xb + (size_t)tn * FF);
                    pf0 = s[tid]; if (tid < 104) pf1 = s[256 + tid];
                }
            }
            __syncthreads();
            const bool rs = ((t & 15) == 15);
            if (tid < SS) {
                float y = 0.0f;
                #pragma unroll
                for (int cc = 0; cc < 8; ++cc) y += sh_part[cc * SS + tid];
                v = y * pe;
                if (rs) {
                    float m = v;
                    #pragma unroll
                    for (int off = 32; off >= 1; off >>= 1)
                        m = fmaxf(m, __shfl_xor(m, off, 64));
                    if ((tid & 63) == 0) sh_red[tid >> 6] = m;
                }
            }
            if (rs) {
                const int tn = (b + 1) * 16;
                if (tn < nf) {
                    float4* dst = (float4*)xbuf[(b + 1) & 1];
                    dst[tid] = pf0; if (tid < 104) dst[256 + tid] = pf1;
                }
                __syncthreads();
                if (tid < SS) {
                    float mm = fmaxf(fmaxf(sh_red[0], sh_red[1]), 1e-37f);
                    v *= (1.0f / mm); logM += __logf(mm);
                }
            }
            if (tid < SS) sh_v[tid] = v;
            __syncthreads();
        }
        if (tid < SS) {
            float ssum = v;
            #pragma unroll
            for (int off = 32; off >= 1; off >>= 1) ssum += __shfl_xor(ssum, off, 64);
            if ((tid & 63) == 0) sh_red[2 + (tid >> 6)] = ssum;
        }
        __syncthreads();
        if (tid == 0) ws[n] = logM + __logf(sh_red[2] + sh_red[3]);
    } else {
        const int w = tid >> 6, l = tid & 63;
        const int n = (blockIdx.x - NB) * 4 + w;
        const int nf = sup[n * 3 + 2];
        const float* xb = x + (size_t)n * TT * FF;
        const int* nl = num_labels + n * LL;
        int li[4];
        #pragma unroll
        for (int k = 0; k < 4; ++k) li[k] = nl[min(4 * l + k, LL - 1)];
        float a4[4] = {NEGV, NEGV, NEGV, NEGV};
        float ea[4], eb[4];
        #pragma unroll
        for (int k = 0; k < 4; ++k) ea[k] = xb[li[k]];
        { const float* xr = xb + (size_t)min(1, nf - 1) * FF;
          #pragma unroll
          for (int k = 0; k < 4; ++k) eb[k] = xr[li[k]]; }
        auto step = [&](float (&ee)[4], int t) {
            float left = __shfl_up(a4[3], 1, 64);
            if (l == 0) left = (t == 0) ? 0.0f : NEGV;
            float prev = left;
            #pragma unroll
            for (int k = 0; k < 4; ++k) {
                const float a = a4[k], b = prev;
                const float mx = fmaxf(a, b), mn = fminf(a, b);
                const float nv = mx + __logf(1.0f + __expf(mn - mx)) + ee[k];
                prev = a4[k]; a4[k] = nv;
            }
            const int t2 = min(t + 2, nf - 1);
            const float* xr = xb + (size_t)t2 * FF;
            #pragma unroll
            for (int k = 0; k < 4; ++k) ee[k] = xr[li[k]];
        };
        int t = 0;
        while (t < nf) { step(ea, t); ++t; if (t >= nf) break; step(eb, t); ++t; }
        const int idx = num_lens[n] - 1;
        if ((idx >> 2) == l) {
            const int kk = idx & 3;
            float vv = (kk == 0) ? a4[0] : (kk == 1) ? a4[1] : (kk == 2) ? a4[2] : a4[3];
            ws[NB + n] = vv;
        }
    }
}

extern "C" void kernel_launch(void* const* d_in, const int* in_sizes, int n_in,
                              void* d_out, int out_size, void* d_ws, size_t ws_size,
                              hipStream_t stream) {
    const float* x          = (const float*)d_in[0];
    const int*   sup        = (const int*)d_in[1];
    const float* trans      = (const float*)d_in[2];
    const int*   den_labels = (const int*)d_in[3];
    const int*   num_labels = (const int*)d_in[4];
    const int*   num_lens   = (const int*)d_in[5];
    float* out = (float*)d_out;

    const size_t PBYTES = (size_t)NB * DNODES * 32768;              // 8,388,608
    const size_t BBYTES = (size_t)NB * QNODES * 201 * BST * 2;      // 5,763,072
    const size_t SCB    = (size_t)NB * DNODES * 8 * sizeof(float);  // 32,768
    const size_t SOFF   = PBYTES + BBYTES;
    const size_t DOFF   = SOFF + SCB;              // dsc (64 floats)
    const size_t COFF   = DOFF + 256;              // counter
    const size_t NEEDED = COFF + 256;

    if (ws_size >= NEEDED) {
        unsigned*  Pout    = (unsigned*)d_ws;
        _Float16*  Bd      = (_Float16*)((char*)d_ws + PBYTES);
        float*     scales8 = (float*)((char*)d_ws + SOFF);
        float*     dsc     = (float*)((char*)d_ws + DOFF);
        int*       ctr     = (int*)((char*)d_ws + COFF);
        hipMemsetAsync(ctr, 0, 64, stream);
        mmi_nodes<<<dim3(512), dim3(512), 0, stream>>>(
            x, sup, trans, den_labels, num_labels, Pout, scales8, Bd);
        mmi_chain<<<dim3(2 * NB), dim3(512), 0, stream>>>(
            (const unsigned short*)d_ws, Bd, scales8, num_lens, sup,
            dsc, ctr, out);
    } else {
        float* ws = (float*)d_ws;
        mmi_forward_fb<<<dim3(20), dim3(256), 0, stream>>>(
            x, sup, trans, den_labels, num_labels, num_lens, ws);
        mmi_finalize<<<dim3(1), dim3(64), 0, stream>>>(ws, sup, out);
    }
}

// Round 8
// 175.412 us; speedup vs baseline: 1.9820x; 1.1241x over previous
//
#include <hip/hip_runtime.h>
#include <math.h>

#define NB 16
#define TT 800
#define FF 90
#define SS 128
#define LL 200
#define NEGV (-1e30f)

#define DNODES 16    // den nodes per utterance
#define DNDRX 50     // den frames per node (16*50 = 800)
#define QNODES 32    // num nodes per utterance
#define QDRX 25      // num frames per node
#define BROW 26      // band diagonals (QDRX+1)
#define BST 28       // Bd row stride in halves (56B, 8B-aligned)
#define NEGH (-60000.0f)
#define EPAD 228     // padded num emission row (200 + 26 + slack)
#define LN2F 0.69314718055994531f
#define LOG2E 1.4426950408889634f

typedef __attribute__((ext_vector_type(8))) short short8;
typedef __attribute__((ext_vector_type(4))) float float4v;
typedef _Float16 h4 __attribute__((ext_vector_type(4)));   // 8B vector of halves

static __device__ __forceinline__ unsigned short f2bf(float x) {
    union { float f; unsigned u; } v; v.f = x;
    unsigned r = (v.u + 0x7FFFu + ((v.u >> 16) & 1u)) >> 16;
    return (unsigned short)r;
}
// truncating bf16 pair pack in ONE VALU op (v_perm_b32), non-negative values
static __device__ __forceinline__ unsigned packperm(float a, float b) {
    return __builtin_amdgcn_perm(__float_as_uint(b), __float_as_uint(a),
                                 0x07060302u);
}
// XOR swizzle of 16B slots within a 64-word X row (validated r5)
static __device__ __forceinline__ int xsw(int row, int wrd) {
    return (wrd & 3) | ((((wrd >> 2) ^ (row & 7)) << 2));
}

// ======================= Kernel A ===========================================
// 512 blocks x 512 threads (8 waves). Dens (blocks 0..255) dispatch first.
//   den block: per-wave 16-row x 128-col running product, ZERO barriers in
//       the t-loop. X rows XOR-swizzled. Emissions stored as PACKED BF16 in
//       lane-permuted layout P[k][q][mt][2] -> each lane's 32 values are one
//       contiguous 64B read (4 x b128 instead of 8): cuts the dominant LDS
//       traffic term ~25%.
//   num block: TWO band nodes, column-parallel, triangle-cut inner loop.
__global__ __launch_bounds__(512, 2) void mmi_nodes(
    const float* __restrict__ x,
    const int*   __restrict__ sup,
    const float* __restrict__ trans,
    const int*   __restrict__ den_labels,
    const int*   __restrict__ num_labels,
    unsigned*    __restrict__ Pout,     // [NB*DNODES][8192] u32 (bf16 pairs)
    float*       __restrict__ scales8,  // [NB*DNODES][8] pow2 exps per row grp
    _Float16*    __restrict__ Bd)       // [NB*QNODES][201][BST]
{
    __shared__ __align__(16) unsigned char SMEM[45632];
    const int tid = threadIdx.x;

    if (blockIdx.x < NB * DNODES) {
        // ---------------- den node product ----------------
        const int bid = blockIdx.x;
        const int u  = bid >> 4;
        const int nd = bid & 15;
        const int t0 = nd * DNDRX;
        const int nf = sup[u * 3 + 2];
        unsigned* Pg = Pout + (size_t)bid * 8192;

        if (t0 >= nf) {   // frozen node -> identity
            #pragma unroll
            for (int k2 = 0; k2 < 16; ++k2) {
                const int ww = tid + k2 * 512;
                const int row = ww >> 6, colw = ww & 63;
                unsigned val = 0;
                if (row == 2 * colw)     val |= 0x3F80u;
                if (row == 2 * colw + 1) val |= 0x3F800000u;
                Pg[ww] = val;
            }
            if (tid < 8) scales8[bid * 8 + tid] = 0.0f;
            return;
        }

        const int w = tid >> 6, l = tid & 63;
        const int m15 = l & 15, q = l >> 4, h = m15 & 7;

        // ---- stage A = exp(T)^T fragments through LDS (one-shot) ----
        unsigned* AFs = (unsigned*)SMEM;              // 8192 u32 = 32 KB
        #pragma unroll
        for (int i = 0; i < 16; ++i) {
            const int wi = tid + i * 512;             // 0..8191
            const int f  = wi >> 2, j2 = wi & 3;
            const int fl = f & 63, kc = (f >> 6) & 3, mt = f >> 8;
            const int col = mt * 16 + (fl & 15);
            const int krow = kc * 32 + (fl >> 4) * 8 + 2 * j2;
            const float a = __expf(trans[(krow    ) * SS + col]);
            const float b = __expf(trans[(krow + 1) * SS + col]);
            AFs[wi] = (unsigned)f2bf(a) | ((unsigned)f2bf(b) << 16);
        }
        __syncthreads();
        short8 afrag[8][4];
        #pragma unroll
        for (int mt = 0; mt < 8; ++mt)
            #pragma unroll
            for (int kc = 0; kc < 4; ++kc)
                afrag[mt][kc] =
                    *(const short8*)(AFs + ((mt * 4 + kc) * 64 + l) * 4);
        __syncthreads();   // WAR: AFs region becomes Xs below

        unsigned* Xs    = (unsigned*)SMEM;            // 8*16*64*4 = 32768 B
        unsigned* ptabH = (unsigned*)(SMEM + 32768);  // 50*64*4 = 12800 B

        // stage emissions: packed bf16 pairs, permuted P[k][q][mt][2]
        // pair index pr = mt*8 + 2q + t holds cols (2pr, 2pr+1)
        for (int idx = tid; idx < DNDRX * 64; idx += 512) {
            const int k = idx >> 6, r = idx & 63;
            const int q2 = r >> 4, mtt = r & 15;
            const int pr = (mtt >> 1) * 8 + 2 * q2 + (mtt & 1);
            const int fr = min(t0 + k, TT - 1);
            const float* xr = x + ((size_t)u * TT + fr) * FF;
            const float ea = __expf(xr[den_labels[2 * pr]]);
            const float eb = __expf(xr[den_labels[2 * pr + 1]]);
            ptabH[idx] = (unsigned)f2bf(ea) | ((unsigned)f2bf(eb) << 16);
        }
        __syncthreads();   // last block-wide barrier

        // per-wave init of own 16 rows: X0 = exp(T) * p0 (swizzled store)
        unsigned* Xw = Xs + w * (16 * 64);
        {
            // lane l needs pair l -> uidx = ((l&7)>>1)*16 + (l>>3)*2 + (l&1)
            const unsigned pp = ptabH[((l & 7) >> 1) * 16 + (l >> 3) * 2 +
                                      (l & 1)];
            const float p0 = __uint_as_float(pp << 16);
            const float p1 = __uint_as_float(pp & 0xFFFF0000u);
            #pragma unroll
            for (int k2 = 0; k2 < 16; ++k2) {
                const int R = w * 16 + k2;
                const float2 t2 = ((const float2*)trans)[R * 64 + l];
                Xw[k2 * 64 + xsw(k2, l)] = packperm(__expf(t2.x) * p0,
                                                    __expf(t2.y) * p1);
            }
        }

        const unsigned short* XwH = (const unsigned short*)Xw;
        const int kmax = min(DNDRX, nf - t0);
        int eacc = 0;
        float redmax = 1.0f;

        for (int k = 1; k < kmax; ++k) {
            // pow2 renorm every 4th step, per-wave
            const bool dosc = ((k & 3) == 0);
            float sc = 1.0f;
            if (dosc) {
                const float mm = fmaxf(redmax, 1e-37f);
                const int e = (int)((__float_as_uint(mm) >> 23) & 255u);
                sc = __uint_as_float((unsigned)(254 - e) << 23);
                eacc += (e - 127);
            }

            short8 bf[4];
            #pragma unroll
            for (int kc = 0; kc < 4; ++kc)
                bf[kc] = *(const short8*)(XwH + m15 * 128 +
                                          8 * (((kc << 2) | q) ^ h));

            float4v acc[8];
            #pragma unroll
            for (int mt = 0; mt < 8; ++mt) {
                float4v z = {0.f, 0.f, 0.f, 0.f};
                acc[mt] = z;
            }
            __builtin_amdgcn_s_setprio(1);
            #pragma unroll
            for (int kc = 0; kc < 4; ++kc)
                #pragma unroll
                for (int mt = 0; mt < 8; ++mt)
                    acc[mt] = __builtin_amdgcn_mfma_f32_16x16x32_bf16(
                        afrag[mt][kc], bf[kc], acc[mt], 0, 0, 0);
            __builtin_amdgcn_s_setprio(0);

            // emission: 4 x b128 packed-bf16 loads (lane-contiguous layout)
            const bool dmax = ((k & 3) == 3);
            float vmax = 0.0f;
            const unsigned* pcb = ptabH + k * 64 + q * 16;
            #pragma unroll
            for (int i = 0; i < 4; ++i) {
                const uint4 pu = *(const uint4*)(pcb + 4 * i);
                float f0 = __uint_as_float(pu.x << 16);
                float f1 = __uint_as_float(pu.x & 0xFFFF0000u);
                float f2 = __uint_as_float(pu.y << 16);
                float f3 = __uint_as_float(pu.y & 0xFFFF0000u);
                float f4 = __uint_as_float(pu.z << 16);
                float f5 = __uint_as_float(pu.z & 0xFFFF0000u);
                float f6 = __uint_as_float(pu.w << 16);
                float f7 = __uint_as_float(pu.w & 0xFFFF0000u);
                if (dosc) {
                    f0 *= sc; f1 *= sc; f2 *= sc; f3 *= sc;
                    f4 *= sc; f5 *= sc; f6 *= sc; f7 *= sc;
                }
                acc[2 * i][0] *= f0;
                acc[2 * i][1] *= f1;
                acc[2 * i][2] *= f2;
                acc[2 * i][3] *= f3;
                acc[2 * i + 1][0] *= f4;
                acc[2 * i + 1][1] *= f5;
                acc[2 * i + 1][2] *= f6;
                acc[2 * i + 1][3] *= f7;
                if (dmax) {
                    vmax = fmaxf(vmax,
                        fmaxf(fmaxf(acc[2 * i][0], acc[2 * i][1]),
                              fmaxf(acc[2 * i][2], acc[2 * i][3])));
                    vmax = fmaxf(vmax,
                        fmaxf(fmaxf(acc[2 * i + 1][0], acc[2 * i + 1][1]),
                              fmaxf(acc[2 * i + 1][2], acc[2 * i + 1][3])));
                }
            }
            if (dmax) {
                #pragma unroll
                for (int off = 32; off >= 1; off >>= 1)
                    vmax = fmaxf(vmax, __shfl_xor(vmax, off, 64));
                redmax = vmax;
            }

            // in-place swizzled write; same-wave lgkmcnt ordering, no barrier
            #pragma unroll
            for (int mt = 0; mt < 8; ++mt) {
                uint2 pk;
                pk.x = packperm(acc[mt][0], acc[mt][1]);
                pk.y = packperm(acc[mt][2], acc[mt][3]);
                *(uint2*)(Xw + m15 * 64 +
                          4 * (((mt << 1) | (q >> 1)) ^ h) + 2 * (q & 1)) = pk;
            }
        }

        // epilogue: wave writes its own rows (un-swizzle on read)
        #pragma unroll
        for (int k2 = 0; k2 < 16; ++k2)
            Pg[(w * 16 + k2) * 64 + l] = Xw[k2 * 64 + xsw(k2, l)];
        if (l == 0) scales8[bid * 8 + w] = (float)eacc;
        return;
    }

    // ---------------- num band products: 2 nodes/block, column-parallel -----
    {
        float* est = (float*)(SMEM + 16);          // [2][25][EPAD] f32

        const int qb    = blockIdx.x - NB * DNODES;
        const int slot0 = qb * 2;
        const int u     = slot0 / QNODES;          // both nodes in same utt
        const int nd0   = slot0 - u * QNODES;
        const int nf    = sup[u * 3 + 2];
        const int* nlu  = num_labels + u * LL;

        for (int idx = tid; idx < 2 * QDRX * EPAD; idx += 512) {
            const int g   = idx / (QDRX * EPAD);
            const int rem = idx - g * (QDRX * EPAD);
            const int tt  = rem / EPAD;
            const int j   = rem - tt * EPAD;
            const int jj  = min(j, 199);
            const int fr  = min((nd0 + g) * QDRX + tt, TT - 1);
            est[idx] = x[((size_t)u * TT + fr) * FF + nlu[jj]] * LOG2E;
        }
        __syncthreads();

        const int g  = tid >> 8;       // node half 0/1
        const int c  = tid & 255;      // band source column (row r = c + d)
        const int nd = nd0 + g;
        const int t0 = nd * QDRX;
        const int kmaxg = min(QDRX, max(nf - t0, 0));
        const float* eg = est + g * (QDRX * EPAD);

        // a[d] = B[c+d][d]: forward alpha of a unit mass started at row c.
        float a[BROW];
        a[0] = 0.0f;
        #pragma unroll
        for (int d = 1; d < BROW; ++d) a[d] = NEGV;

        const float* etc = eg + (c - 1);
        for (int t = 0; t < kmaxg; ++t, etc += EPAD) {
            const int tc = t + 1;   // wave-uniform live-band bound
            #pragma unroll
            for (int d = BROW - 1; d >= 1; --d) {
                if (d <= tc) {
                    const float e  = etc[d];    // emission of row c+d
                    const float aa = a[d], bb = a[d - 1];
                    const float mx = fmaxf(aa, bb);
                    const float dd = fminf(aa, bb) - mx;
                    a[d] = e + mx +
                           __builtin_amdgcn_logf(
                               1.0f + __builtin_amdgcn_exp2f(dd));
                }
            }
            // d = 0: self-loop at row c (row 0 cannot persist)
            a[0] = (c == 0) ? NEGV : (etc[0] + a[0]);
        }

        if (c <= 200) {
            _Float16* Bg = Bd + (size_t)(slot0 + g) * 201 * BST;
            #pragma unroll
            for (int d = 0; d < BROW; ++d) {
                const int r = c + d;
                if (r <= 200) Bg[r * BST + d] = (_Float16)fmaxf(a[d], NEGH);
            }
            if (c < BROW - 1) {   // fill k > r triangle (unreachable transfers)
                for (int kk = c + 1; kk < BROW; ++kk)
                    Bg[c * BST + kk] = (_Float16)NEGH;
            }
        }
    }
}

// ======================= Kernel B: chains + fused finalize ==================
// 256 threads (r5-validated den chain); num chain with 8B vector loads.
__global__ __launch_bounds__(256) void mmi_chain(
    const unsigned short* __restrict__ Pmat,   // [16][DNODES][128*128] bf16
    const _Float16* __restrict__ Bd,           // [16][QNODES][201][BST]
    const float* __restrict__ scales8,         // [16*DNODES][8]
    const int* __restrict__ num_lens,
    const int* __restrict__ sup,
    float* __restrict__ dsc,                   // [0..15] den, [16..31] num
    unsigned* __restrict__ ctr,                // completion counter (modulo)
    float* __restrict__ out)
{
    __shared__ float sh_v[SS];
    __shared__ float sh_part[8 * SS];
    __shared__ float sh_red[2];
    __shared__ float ab[2][232];
    __shared__ int sfl;

    const int tid = threadIdx.x;

    if (blockIdx.x < NB) {
        const int u = blockIdx.x;
        const int gg = tid & 31, c = tid >> 5;
        const unsigned short* Pu = Pmat + (size_t)u * DNODES * 16384;

        if (tid < SS) sh_v[tid] = (tid == 0) ? 1.0f : 0.0f;
        int   e2acc = 0;
        float sscal = 0.0f;

        uint2 curm[16], nxt[16];
        #pragma unroll
        for (int j = 0; j < 16; ++j)
            curm[j] = *(const uint2*)(Pu + (16 * c + j) * SS + 4 * gg);
        __syncthreads();

        for (int i = 0; i < DNODES; ++i) {
            if (i + 1 < DNODES) {
                const unsigned short* Pn = Pu + (size_t)(i + 1) * 16384;
                #pragma unroll
                for (int j = 0; j < 16; ++j)
                    nxt[j] = *(const uint2*)(Pn + (16 * c + j) * SS + 4 * gg);
            }
            const float* s8 = scales8 + (size_t)(u * DNODES + i) * 8;
            float gmax = s8[0];
            #pragma unroll
            for (int g2 = 1; g2 < 8; ++g2) gmax = fmaxf(gmax, s8[g2]);
            const float fgr = __builtin_amdgcn_exp2f(s8[c] - gmax);
            sscal += gmax;

            const float4* av = (const float4*)(sh_v + 16 * c);
            float4 aa[4] = {av[0], av[1], av[2], av[3]};
            const float* as = (const float*)aa;
            float4 acc = make_float4(0.f, 0.f, 0.f, 0.f);
            #pragma unroll
            for (int j = 0; j < 16; ++j) {
                const float e0 = __uint_as_float(curm[j].x << 16);
                const float e1 = __uint_as_float(curm[j].x & 0xFFFF0000u);
                const float e2 = __uint_as_float(curm[j].y << 16);
                const float e3 = __uint_as_float(curm[j].y & 0xFFFF0000u);
                acc.x = fmaf(as[j], e0, acc.x);
                acc.y = fmaf(as[j], e1, acc.y);
                acc.z = fmaf(as[j], e2, acc.z);
                acc.w = fmaf(as[j], e3, acc.w);
            }
            acc.x *= fgr; acc.y *= fgr; acc.z *= fgr; acc.w *= fgr;
            *(float4*)(sh_part + c * SS + 4 * gg) = acc;
            __syncthreads();

            float v = 0.0f;
            if (tid < SS) {
                float y = 0.0f;
                #pragma unroll
                for (int cc = 0; cc < 8; ++cc) y += sh_part[cc * SS + tid];
                v = y;
                float m = v;
                #pragma unroll
                for (int off = 32; off >= 1; off >>= 1)
                    m = fmaxf(m, __shfl_xor(m, off, 64));
                if ((tid & 63) == 0) sh_red[tid >> 6] = m;
            }
            __syncthreads();
            if (tid < SS) {
                const float mm = fmaxf(fmaxf(sh_red[0], sh_red[1]), 1e-37f);
                const int e = (int)((__float_as_uint(mm) >> 23) & 255u);
                const float inv = __uint_as_float((unsigned)(254 - e) << 23);
                e2acc += (e - 127);
                sh_v[tid] = v * inv;
            }
            #pragma unroll
            for (int j = 0; j < 16; ++j) curm[j] = nxt[j];
            __syncthreads();
        }

        if (tid < SS) {
            float s = sh_v[tid];
            #pragma unroll
            for (int off = 32; off >= 1; off >>= 1)
                s += __shfl_xor(s, off, 64);
            if ((tid & 63) == 0) sh_red[tid >> 6] = s;
        }
        __syncthreads();
        if (tid == 0)
            atomicExch(&dsc[u], LN2F * ((float)e2acc + sscal) +
                                __logf(sh_red[0] + sh_red[1]));
    } else {
        // ---------------- num chain: band matvecs ----------------
        const int u = blockIdx.x - NB;
        const _Float16* Bu = Bd + (size_t)u * QNODES * 201 * BST;
        const int r = tid;
        const bool act = (r < 201);

        if (r < 232) { ab[0][r] = NEGV; ab[1][r] = NEGV; }
        h4 nx1[7], nx2[7];
        float dv[BROW];
        if (act) {
            const h4* s0 = (const h4*)(Bu + (size_t)r * BST);
            #pragma unroll
            for (int t7 = 0; t7 < 7; ++t7) nx1[t7] = s0[t7];
            #pragma unroll
            for (int k = 0; k < BROW; ++k) dv[k] = (float)nx1[k >> 2][k & 3];
            const h4* s1 = (const h4*)(Bu + ((size_t)201 + r) * BST);
            #pragma unroll
            for (int t7 = 0; t7 < 7; ++t7) nx1[t7] = s1[t7];
        }
        __syncthreads();
        if (r == 0) ab[0][QDRX] = 0.0f;    // alpha[0] = 0 (log2), offset QDRX
        __syncthreads();

        int cur = 0;
        for (int nd = 0; nd < QNODES; ++nd) {
            if (nd + 2 < QNODES && act) {
                const h4* src = (const h4*)(Bu + ((size_t)(nd + 2) * 201 + r) * BST);
                #pragma unroll
                for (int t7 = 0; t7 < 7; ++t7) nx2[t7] = src[t7];
            }
            float anew = NEGV;
            if (act) {
                float tr[BROW];
                #pragma unroll
                for (int k = 0; k < BROW; ++k)
                    tr[k] = dv[k] + ab[cur][QDRX + r - k];
                float m = tr[0];
                #pragma unroll
                for (int k = 1; k < BROW; ++k) m = fmaxf(m, tr[k]);
                float s = 0.0f;
                #pragma unroll
                for (int k = 0; k < BROW; ++k)
                    s += __builtin_amdgcn_exp2f(tr[k] - m);
                anew = m + __builtin_amdgcn_logf(s);
            }
            if (act) ab[cur ^ 1][QDRX + r] = anew;
            cur ^= 1;
            __syncthreads();
            if (act) {
                #pragma unroll
                for (int k = 0; k < BROW; ++k) dv[k] = (float)nx1[k >> 2][k & 3];
                #pragma unroll
                for (int t7 = 0; t7 < 7; ++t7) nx1[t7] = nx2[t7];
            }
        }
        if (r == 0)
            atomicExch(&dsc[NB + u], ab[cur][QDRX + num_lens[u]] * LN2F);
    }

    // ---------------- fused finalize: last chain block ----------------
    // modulo-32 completion test: correct for any ctr start value, so no
    // memset enqueue is needed across graph replays.
    __threadfence();
    if (tid == 0) sfl = ((atomicAdd(ctr, 1u) & 31u) == 31u);
    __syncthreads();
    if (!sfl) return;
    __threadfence();
    if (tid < 64) {
        float tot_score = 0.0f, tot_frames = 0.0f, all_frames = 0.0f;
        if (tid < NB) {
            const float d = atomicAdd(&dsc[tid], 0.0f);       // coherent read
            const float n = atomicAdd(&dsc[NB + tid], 0.0f);
            const float tot = n - d;
            const int nf = sup[tid * 3 + 2];
            const bool fin = isfinite(tot) && (tot > 0.5f * NEGV);
            tot_score  = fin ? tot : 0.0f;
            tot_frames = fin ? (float)nf : 0.0f;
            all_frames = (float)nf;
        }
        #pragma unroll
        for (int off = 32; off >= 1; off >>= 1) {
            tot_score  += __shfl_xor(tot_score, off, 64);
            tot_frames += __shfl_xor(tot_frames, off, 64);
            all_frames += __shfl_xor(all_frames, off, 64);
        }
        if (tid == 0) {
            out[0] = tot_score;
            out[1] = tot_frames;
            out[2] = all_frames;
        }
    }
}

// ======================= Finalize (fallback path only) ======================
__global__ void mmi_finalize(const float* __restrict__ sc,
                             const int* __restrict__ sup,
                             float* __restrict__ out)
{
    const int tid = threadIdx.x;
    float tot_score = 0.0f, tot_frames = 0.0f, all_frames = 0.0f;
    if (tid < NB) {
        const float tot = sc[NB + tid] - sc[tid];
        const int nf = sup[tid * 3 + 2];
        const bool fin = isfinite(tot) && (tot > 0.5f * NEGV);
        tot_score  = fin ? tot : 0.0f;
        tot_frames = fin ? (float)nf : 0.0f;
        all_frames = (float)nf;
    }
    #pragma unroll
    for (int off = 32; off >= 1; off >>= 1) {
        tot_score  += __shfl_xor(tot_score, off, 64);
        tot_frames += __shfl_xor(tot_frames, off, 64);
        all_frames += __shfl_xor(all_frames, off, 64);
    }
    if (tid == 0) {
        out[0] = tot_score;
        out[1] = tot_frames;
        out[2] = all_frames;
    }
}

// ======================= Fallback (validated round-4 kernel) =================
#define XBF (16 * FF)
__global__ __launch_bounds__(256) void mmi_forward_fb(
    const float* __restrict__ x, const int* __restrict__ sup,
    const float* __restrict__ trans, const int* __restrict__ den_labels,
    const int* __restrict__ num_labels, const int* __restrict__ num_lens,
    float* __restrict__ ws)
{
    const int tid = threadIdx.x;
    if (blockIdx.x < NB) {
        __shared__ float sh_v[SS];
        __shared__ float sh_part[8 * SS];
        __shared__ float sh_red[4];
        __shared__ __align__(16) float xbuf[2][XBF];
        const int n = blockIdx.x, nf = sup[n * 3 + 2];
        const int g = tid & 31, c = tid >> 5;
        float4 e[16];
        #pragma unroll
        for (int j = 0; j < 16; ++j) {
            const float4 t4 = *(const float4*)(trans + (size_t)(16 * c + j) * SS + 4 * g);
            e[j] = make_float4(__expf(t4.x), __expf(t4.y), __expf(t4.z), __expf(t4.w));
        }
        const int lab = (tid < SS) ? den_labels[tid & (SS - 1)] : 0;
        const float* xb = x + (size_t)n * TT * FF;
        {
            const float4* s0 = (const float4*)xb;
            float4 p0 = s0[tid]; float4 p1; if (tid < 104) p1 = s0[256 + tid];
            float4* d0 = (float4*)xbuf[0];
            d0[tid] = p0; if (tid < 104) d0[256 + tid] = p1;
        }
        if (tid < SS) sh_v[tid] = (tid == 0) ? 1.0f : 0.0f;
        float logM = 0.0f, v = 0.0f, pe = 0.0f;
        float4 pf0, pf1;
        __syncthreads();
        for (int t = 0; t < nf; ++t) {
            const int b = t >> 4;
            if (tid < SS) pe = __expf(xbuf[b & 1][(t & 15) * FF + lab]);
            float4 aa[4];
            { const float4* av = (const float4*)(sh_v + 16 * c);
              aa[0] = av[0]; aa[1] = av[1]; aa[2] = av[2]; aa[3] = av[3]; }
            const float* as = (const float*)aa;
            float4 acc = make_float4(0.f, 0.f, 0.f, 0.f);
            #pragma unroll
            for (int j = 0; j < 16; ++j) {
                acc.x = fmaf(as[j], e[j].x, acc.x); acc.y = fmaf(as[j], e[j].y, acc.y);
                acc.z = fmaf(as[j], e[j].z, acc.z); acc.w = fmaf(as[j], e[j].w, acc.w);
            }
            *(float4*)(sh_part + c * SS + 4 * g) = acc;
            if ((t & 15) == 8) {
                const int tn = (b + 1) * 16;
                if (tn < nf) {
                    const float4* s = (const float4*)(xb + (size_t)tn * FF);
                    pf0 = s[tid]; if (tid < 104) pf1 = s[256 + tid];
                }
            }
            __syncthreads();
            const bool rs = ((t & 15) == 15);
            if (tid < SS) {
                float y = 0.0f;
                #pragma unroll
                for (int cc = 0; cc < 8; ++cc) y += sh_part[cc * SS + tid];
                v = y * pe;
                if (rs) {
                    float m = v;
                    #pragma unroll
                    for (int off = 32; off >= 1; off >>= 1)
                        m = fmaxf(m, __shfl_xor(m, off, 64));
                    if ((tid & 63) == 0) sh_red[tid >> 6] = m;
                }
            }
            if (rs) {
                const int tn = (b + 1) * 16;
                if (tn < nf) {
                    float4* dst = (float4*)xbuf[(b + 1) & 1];
                    dst[tid] = pf0; if (tid < 104) dst[256 + tid] = pf1;
                }
                __syncthreads();
                if (tid < SS) {
                    float mm = fmaxf(fmaxf(sh_red[0], sh_red[1]), 1e-37f);
                    v *= (1.0f / mm); logM += __logf(mm);
                }
            }
            if (tid < SS) sh_v[tid] = v;
            __syncthreads();
        }
        if (tid < SS) {
            float ssum = v;
            #pragma unroll
            for (int off = 32; off >= 1; off >>= 1) ssum += __shfl_xor(ssum, off, 64);
            if ((tid & 63) == 0) sh_red[2 + (tid >> 6)] = ssum;
        }
        __syncthreads();
        if (tid == 0) ws[n] = logM + __logf(sh_red[2] + sh_red[3]);
    } else {
        const int w = tid >> 6, l = tid & 63;
        const int n = (blockIdx.x - NB) * 4 + w;
        const int nf = sup[n * 3 + 2];
        const float* xb = x + (size_t)n * TT * FF;
        const int* nl = num_labels + n * LL;
        int li[4];
        #pragma unroll
        for (int k = 0; k < 4; ++k) li[k] = nl[min(4 * l + k, LL - 1)];
        float a4[4] = {NEGV, NEGV, NEGV, NEGV};
        float ea[4], eb[4];
        #pragma unroll
        for (int k = 0; k < 4; ++k) ea[k] = xb[li[k]];
        { const float* xr = xb + (size_t)min(1, nf - 1) * FF;
          #pragma unroll
          for (int k = 0; k < 4; ++k) eb[k] = xr[li[k]]; }
        auto step = [&](float (&ee)[4], int t) {
            float left = __shfl_up(a4[3], 1, 64);
            if (l == 0) left = (t == 0) ? 0.0f : NEGV;
            float prev = left;
            #pragma unroll
            for (int k = 0; k < 4; ++k) {
                const float a = a4[k], b = prev;
                const float mx = fmaxf(a, b), mn = fminf(a, b);
                const float nv = mx + __logf(1.0f + __expf(mn - mx)) + ee[k];
                prev = a4[k]; a4[k] = nv;
            }
            const int t2 = min(t + 2, nf - 1);
            const float* xr = xb + (size_t)t2 * FF;
            #pragma unroll
            for (int k = 0; k < 4; ++k) ee[k] = xr[li[k]];
        };
        int t = 0;
        while (t < nf) { step(ea, t); ++t; if (t >= nf) break; step(eb, t); ++t; }
        const int idx = num_lens[n] - 1;
        if ((idx >> 2) == l) {
            const int kk = idx & 3;
            float vv = (kk == 0) ? a4[0] : (kk == 1) ? a4[1] : (kk == 2) ? a4[2] : a4[3];
            ws[NB + n] = vv;
        }
    }
}

extern "C" void kernel_launch(void* const* d_in, const int* in_sizes, int n_in,
                              void* d_out, int out_size, void* d_ws, size_t ws_size,
                              hipStream_t stream) {
    const float* x          = (const float*)d_in[0];
    const int*   sup        = (const int*)d_in[1];
    const float* trans      = (const float*)d_in[2];
    const int*   den_labels = (const int*)d_in[3];
    const int*   num_labels = (const int*)d_in[4];
    const int*   num_lens   = (const int*)d_in[5];
    float* out = (float*)d_out;

    const size_t PBYTES = (size_t)NB * DNODES * 32768;              // 8,388,608
    const size_t BBYTES = (size_t)NB * QNODES * 201 * BST * 2;      // 5,763,072
    const size_t SCB    = (size_t)NB * DNODES * 8 * sizeof(float);  // 32,768
    const size_t SOFF   = PBYTES + BBYTES;
    const size_t DOFF   = SOFF + SCB;              // dsc (64 floats)
    const size_t COFF   = DOFF + 256;              // counter
    const size_t NEEDED = COFF + 256;

    if (ws_size >= NEEDED) {
        unsigned*  Pout    = (unsigned*)d_ws;
        _Float16*  Bd      = (_Float16*)((char*)d_ws + PBYTES);
        float*     scales8 = (float*)((char*)d_ws + SOFF);
        float*     dsc     = (float*)((char*)d_ws + DOFF);
        unsigned*  ctr     = (unsigned*)((char*)d_ws + COFF);
        mmi_nodes<<<dim3(512), dim3(512), 0, stream>>>(
            x, sup, trans, den_labels, num_labels, Pout, scales8, Bd);
        mmi_chain<<<dim3(2 * NB), dim3(256), 0, stream>>>(
            (const unsigned short*)d_ws, Bd, scales8, num_lens, sup,
            dsc, ctr, out);
    } else {
        float* ws = (float*)d_ws;
        mmi_forward_fb<<<dim3(20), dim3(256), 0, stream>>>(
            x, sup, trans, den_labels, num_labels, num_lens, ws);
        mmi_finalize<<<dim3(1), dim3(64), 0, stream>>>(ws, sup, out);
    }
}

// Round 9
// 167.586 us; speedup vs baseline: 2.0745x; 1.0467x over previous
//
#include <hip/hip_runtime.h>
#include <math.h>

#define NB 16
#define TT 800
#define FF 90
#define SS 128
#define LL 200
#define NEGV (-1e30f)

#define DNODES 16    // den nodes per utterance
#define DNDRX 50     // den frames per node (16*50 = 800)
#define QNODES 32    // num nodes per utterance
#define QDRX 25      // num frames per node
#define BROW 26      // band diagonals (QDRX+1)
#define BST 28       // Bd row stride in halves (56B, 8B-aligned)
#define NEGH (-60000.0f)
#define EPAD 228     // padded num emission row (200 + 26 + slack)
#define LN2F 0.69314718055994531f
#define LOG2E 1.4426950408889634f

typedef __attribute__((ext_vector_type(8))) short short8;
typedef __attribute__((ext_vector_type(16))) float f32x16;
typedef _Float16 h4 __attribute__((ext_vector_type(4)));
typedef unsigned uint2v __attribute__((ext_vector_type(2)));

static __device__ __forceinline__ unsigned short f2bf(float x) {
    union { float f; unsigned u; } v; v.f = x;
    unsigned r = (v.u + 0x7FFFu + ((v.u >> 16) & 1u)) >> 16;
    return (unsigned short)r;
}
// truncating bf16 pair pack in ONE VALU op (v_perm_b32), non-negative values
static __device__ __forceinline__ unsigned packperm(float a, float b) {
    return __builtin_amdgcn_perm(__float_as_uint(b), __float_as_uint(a),
                                 0x07060302u);
}

// ======================= Kernel A ===========================================
// 768 blocks x 256 threads. Dens (blocks 0..255) dispatch first; ~230 regs ->
// 2 waves/SIMD -> 2 blocks/CU -> den and num co-resident from t=0.
//   den block (1 node, 4 waves x 32 rows): X carried ENTIRELY in registers.
//       32x32x16 MFMA; C-frag -> next B-frag via permlane32_swap (half-lane
//       exchange) -- ZERO LDS ops, zero lgkmcnt in the t-loop.
//   num block (1 node, 256 thr): column-parallel band, triangle-cut (r6-
//       validated structure, BST-padded output).
__global__ __launch_bounds__(256, 2) void mmi_nodes(
    const float* __restrict__ x,
    const int*   __restrict__ sup,
    const float* __restrict__ trans,
    const int*   __restrict__ den_labels,
    const int*   __restrict__ num_labels,
    unsigned*    __restrict__ Pout,     // [NB*DNODES][8192] u32 (bf16 pairs)
    float*       __restrict__ scales4,  // [NB*DNODES][4] pow2 exps per wave
    _Float16*    __restrict__ Bd)       // [NB*QNODES][201][BST]
{
    __shared__ __align__(16) unsigned char SMEM[45632];
    const int tid = threadIdx.x;

    if (blockIdx.x < NB * DNODES) {
        // ---------------- den node product (register-resident X) -----------
        const int bid = blockIdx.x;
        const int u  = bid >> 4;
        const int nd = bid & 15;
        const int t0 = nd * DNDRX;
        const int nf = sup[u * 3 + 2];
        unsigned* Pg = Pout + (size_t)bid * 8192;

        if (t0 >= nf) {   // frozen node -> identity
            #pragma unroll
            for (int k2 = 0; k2 < 32; ++k2) {
                const int ww = tid + k2 * 256;
                const int row = ww >> 6, colw = ww & 63;
                unsigned val = 0;
                if (row == 2 * colw)     val |= 0x3F80u;
                if (row == 2 * colw + 1) val |= 0x3F800000u;
                Pg[ww] = val;
            }
            if (tid < 4) scales4[bid * 4 + tid] = 0.0f;
            return;
        }

        const int w = tid >> 6, l = tid & 63;
        const int l31 = l & 31, h = l >> 5;
        const int row = w * 32 + l31;        // this lane's X row

        unsigned* AFs   = (unsigned*)SMEM;            // 8192 u32 = 32 KB
        unsigned* ptabP = (unsigned*)(SMEM + 32768);  // 50*64 u32 = 12.8 KB

        // ---- stage A = E^T fragments (32x32x16 layout) through LDS ----
        // AF frag (mt,kc): lane fl holds A[m=mt*32+(fl&31)][k=kc*16+(fl>>5)*8+j]
        #pragma unroll
        for (int i = 0; i < 32; ++i) {
            const int wi = tid + i * 256;             // 0..8191
            const int f  = wi >> 2, j2 = wi & 3;
            const int fl = f & 63, kc = (f >> 6) & 7, mt = f >> 9;
            const int col = mt * 32 + (fl & 31);
            const int krow = kc * 16 + (fl >> 5) * 8 + 2 * j2;
            const float a = __expf(trans[(krow    ) * SS + col]);
            const float b = __expf(trans[(krow + 1) * SS + col]);
            AFs[wi] = (unsigned)f2bf(a) | ((unsigned)f2bf(b) << 16);
        }
        // ---- stage emissions: packed bf16 pairs, half-permuted layout ----
        // ptabP[k*64 + h*32 + mt*8 + r2*2 + b] = pair of cols (2cp, 2cp+1),
        // cp = 16mt + 4r2 + 2h + b  -> matches acc reg order exactly.
        for (int idx = tid; idx < DNDRX * 64; idx += 256) {
            const int k = idx >> 6, within = idx & 63;
            const int h2 = within >> 5, rem = within & 31;
            const int mt = rem >> 3, r2 = (rem >> 1) & 3, b = rem & 1;
            const int cp = 16 * mt + 4 * r2 + 2 * h2 + b;
            const int fr = min(t0 + k, TT - 1);
            const float* xr = x + ((size_t)u * TT + fr) * FF;
            const float ea = __expf(xr[den_labels[2 * cp]]);
            const float eb = __expf(xr[den_labels[2 * cp + 1]]);
            ptabP[idx] = (unsigned)f2bf(ea) | ((unsigned)f2bf(eb) << 16);
        }
        __syncthreads();

        short8 afrag[4][8];
        #pragma unroll
        for (int mt = 0; mt < 4; ++mt)
            #pragma unroll
            for (int kc = 0; kc < 8; ++kc)
                afrag[mt][kc] =
                    *(const short8*)(AFs + ((mt * 8 + kc) * 64 + l) * 4);

        // ---- init X0 = exp(T) * p0 directly into C-fragment registers ----
        // acc[mt][reg]: col = mt*32 + 8*(reg>>2) + 4h + (reg&3), row fixed.
        f32x16 acc[4];
        #pragma unroll
        for (int mt = 0; mt < 4; ++mt) {
            #pragma unroll
            for (int r2 = 0; r2 < 4; ++r2)
                #pragma unroll
                for (int b = 0; b < 2; ++b) {
                    const float2 t2 = ((const float2*)(trans + (size_t)row * SS +
                                        mt * 32 + 8 * r2 + 4 * h))[b];
                    const unsigned pp = ptabP[h * 32 + mt * 8 + r2 * 2 + b];
                    const float p0 = __uint_as_float(pp << 16);
                    const float p1 = __uint_as_float(pp & 0xFFFF0000u);
                    acc[mt][4 * r2 + 2 * b]     = __expf(t2.x) * p0;
                    acc[mt][4 * r2 + 2 * b + 1] = __expf(t2.y) * p1;
                }
        }

        const int kmax = min(DNDRX, nf - t0);
        int eacc = 0;
        float redmax = 1.0f;

        for (int k = 1; k < kmax; ++k) {
            const bool dosc = ((k & 3) == 0);
            float sc = 1.0f;
            if (dosc) {
                const float mm = fmaxf(redmax, 1e-37f);
                const int e = (int)((__float_as_uint(mm) >> 23) & 255u);
                sc = __uint_as_float((unsigned)(254 - e) << 23);
                eacc += (e - 127);
            }

            // pack X_k (pair p covers acc regs 2p, 2p+1)
            unsigned pk[4][8];
            #pragma unroll
            for (int mt = 0; mt < 4; ++mt)
                #pragma unroll
                for (int p = 0; p < 8; ++p)
                    pk[mt][p] = packperm(acc[mt][2 * p], acc[mt][2 * p + 1]);

            #pragma unroll
            for (int mt = 0; mt < 4; ++mt) {
                f32x16 z = {0.f, 0.f, 0.f, 0.f, 0.f, 0.f, 0.f, 0.f,
                            0.f, 0.f, 0.f, 0.f, 0.f, 0.f, 0.f, 0.f};
                acc[mt] = z;
            }

            // X_{k+1} = X_k * E: B-frag per kc built with 2 permlane32_swap
            #pragma unroll
            for (int kc = 0; kc < 8; ++kc) {
                const int s = kc & 1, mk = kc >> 1;
                const uint2v s1 = __builtin_amdgcn_permlane32_swap(
                    pk[mk][4 * s], pk[mk][4 * s + 2], false, false);
                const uint2v s2 = __builtin_amdgcn_permlane32_swap(
                    pk[mk][4 * s + 1], pk[mk][4 * s + 3], false, false);
                union { unsigned u[4]; short8 s8; } B;
                B.u[0] = s1[0]; B.u[1] = s2[0]; B.u[2] = s1[1]; B.u[3] = s2[1];
                #pragma unroll
                for (int mt = 0; mt < 4; ++mt)
                    acc[mt] = __builtin_amdgcn_mfma_f32_32x32x16_bf16(
                        afrag[mt][kc], B.s8, acc[mt], 0, 0, 0);
            }

            // emission (broadcast b128 reads; layout matches acc reg order)
            const bool dmax = ((k & 3) == 3);
            float vmax = 0.0f;
            const unsigned* pcb = ptabP + k * 64 + h * 32;
            #pragma unroll
            for (int mt = 0; mt < 4; ++mt) {
                #pragma unroll
                for (int half2 = 0; half2 < 2; ++half2) {
                    const uint4 pu = *(const uint4*)(pcb + mt * 8 + 4 * half2);
                    #pragma unroll
                    for (int j = 0; j < 4; ++j) {
                        const unsigned pw = (j == 0) ? pu.x : (j == 1) ? pu.y
                                          : (j == 2) ? pu.z : pu.w;
                        float f0 = __uint_as_float(pw << 16);
                        float f1 = __uint_as_float(pw & 0xFFFF0000u);
                        if (dosc) { f0 *= sc; f1 *= sc; }
                        const int r0 = half2 * 8 + 2 * j;
                        acc[mt][r0]     *= f0;
                        acc[mt][r0 + 1] *= f1;
                        if (dmax)
                            vmax = fmaxf(vmax,
                                fmaxf(acc[mt][r0], acc[mt][r0 + 1]));
                    }
                }
            }
            if (dmax) {
                #pragma unroll
                for (int off = 32; off >= 1; off >>= 1)
                    vmax = fmaxf(vmax, __shfl_xor(vmax, off, 64));
                redmax = vmax;
            }
        }

        // ---- epilogue: bounce through LDS for coalesced Pout write ----
        unsigned* Xo = (unsigned*)SMEM;   // reuse AFs region (32 KB)
        #pragma unroll
        for (int mt = 0; mt < 4; ++mt)
            #pragma unroll
            for (int p = 0; p < 8; ++p) {
                const int cp = 16 * mt + 4 * (p >> 1) + 2 * h + (p & 1);
                Xo[row * 64 + cp] = packperm(acc[mt][2 * p], acc[mt][2 * p + 1]);
            }
        __syncthreads();
        #pragma unroll
        for (int i = 0; i < 32; ++i) {
            const int ww = tid + i * 256;
            Pg[ww] = Xo[ww];
        }
        if (l == 0) scales4[bid * 4 + w] = (float)eacc;
        return;
    }

    // ---------------- num band product: ONE node, column-parallel -----------
    {
        float* est = (float*)SMEM;                 // [25][EPAD] f32 = 22.8 KB

        const int slot = blockIdx.x - NB * DNODES;   // 0..511
        const int u    = slot >> 5;
        const int nd   = slot & 31;
        const int nf   = sup[u * 3 + 2];
        const int* nlu = num_labels + u * LL;

        for (int idx = tid; idx < QDRX * EPAD; idx += 256) {
            const int tt  = idx / EPAD;
            const int j   = idx - tt * EPAD;
            const int jj  = min(j, 199);
            const int fr  = min(nd * QDRX + tt, TT - 1);
            est[idx] = x[((size_t)u * TT + fr) * FF + nlu[jj]] * LOG2E;
        }
        __syncthreads();

        const int c  = tid;            // band source column (row r = c + d)
        const int t0 = nd * QDRX;
        const int kmaxg = min(QDRX, max(nf - t0, 0));

        // a[d] = B[c+d][d]: forward alpha of a unit mass started at row c.
        float a[BROW];
        a[0] = 0.0f;
        #pragma unroll
        for (int d = 1; d < BROW; ++d) a[d] = NEGV;

        const float* etc = est + (c - 1);
        for (int t = 0; t < kmaxg; ++t, etc += EPAD) {
            const int tc = t + 1;   // wave-uniform live-band bound
            #pragma unroll
            for (int d = BROW - 1; d >= 1; --d) {
                if (d <= tc) {
                    const float e  = etc[d];    // emission of row c+d
                    const float aa = a[d], bb = a[d - 1];
                    const float mx = fmaxf(aa, bb);
                    const float dd = fminf(aa, bb) - mx;
                    a[d] = e + mx +
                           __builtin_amdgcn_logf(
                               1.0f + __builtin_amdgcn_exp2f(dd));
                }
            }
            // d = 0: self-loop at row c (row 0 cannot persist)
            a[0] = (c == 0) ? NEGV : (etc[0] + a[0]);
        }

        if (c <= 200) {
            _Float16* Bg = Bd + (size_t)slot * 201 * BST;
            #pragma unroll
            for (int d = 0; d < BROW; ++d) {
                const int r = c + d;
                if (r <= 200) Bg[r * BST + d] = (_Float16)fmaxf(a[d], NEGH);
            }
            if (c < BROW - 1) {   // fill k > r triangle (unreachable transfers)
                for (int kk = c + 1; kk < BROW; ++kk)
                    Bg[c * BST + kk] = (_Float16)NEGH;
            }
        }
    }
}

// ======================= Kernel B: chains + fused finalize ==================
__global__ __launch_bounds__(256) void mmi_chain(
    const unsigned short* __restrict__ Pmat,   // [16][DNODES][128*128] bf16
    const _Float16* __restrict__ Bd,           // [16][QNODES][201][BST]
    const float* __restrict__ scales4,         // [16*DNODES][4]
    const int* __restrict__ num_lens,
    const int* __restrict__ sup,
    float* __restrict__ dsc,                   // [0..15] den, [16..31] num
    unsigned* __restrict__ ctr,                // completion counter (modulo)
    float* __restrict__ out)
{
    __shared__ float sh_v[SS];
    __shared__ float sh_part[8 * SS];
    __shared__ float sh_red[2];
    __shared__ float ab[2][232];
    __shared__ int sfl;

    const int tid = threadIdx.x;

    if (blockIdx.x < NB) {
        const int u = blockIdx.x;
        const int gg = tid & 31, c = tid >> 5;
        const unsigned short* Pu = Pmat + (size_t)u * DNODES * 16384;

        if (tid < SS) sh_v[tid] = (tid == 0) ? 1.0f : 0.0f;
        int   e2acc = 0;
        float sscal = 0.0f;

        uint2 curm[16], nxt[16];
        #pragma unroll
        for (int j = 0; j < 16; ++j)
            curm[j] = *(const uint2*)(Pu + (16 * c + j) * SS + 4 * gg);
        __syncthreads();

        for (int i = 0; i < DNODES; ++i) {
            if (i + 1 < DNODES) {
                const unsigned short* Pn = Pu + (size_t)(i + 1) * 16384;
                #pragma unroll
                for (int j = 0; j < 16; ++j)
                    nxt[j] = *(const uint2*)(Pn + (16 * c + j) * SS + 4 * gg);
            }
            // per-32-row-group pow2 scales of this node
            const float* s4 = scales4 + (size_t)(u * DNODES + i) * 4;
            const float gmax = fmaxf(fmaxf(s4[0], s4[1]), fmaxf(s4[2], s4[3]));
            const float fgr = __builtin_amdgcn_exp2f(s4[c >> 1] - gmax);
            sscal += gmax;

            const float4* av = (const float4*)(sh_v + 16 * c);
            float4 aa[4] = {av[0], av[1], av[2], av[3]};
            const float* as = (const float*)aa;
            float4 acc = make_float4(0.f, 0.f, 0.f, 0.f);
            #pragma unroll
            for (int j = 0; j < 16; ++j) {
                const float e0 = __uint_as_float(curm[j].x << 16);
                const float e1 = __uint_as_float(curm[j].x & 0xFFFF0000u);
                const float e2 = __uint_as_float(curm[j].y << 16);
                const float e3 = __uint_as_float(curm[j].y & 0xFFFF0000u);
                acc.x = fmaf(as[j], e0, acc.x);
                acc.y = fmaf(as[j], e1, acc.y);
                acc.z = fmaf(as[j], e2, acc.z);
                acc.w = fmaf(as[j], e3, acc.w);
            }
            acc.x *= fgr; acc.y *= fgr; acc.z *= fgr; acc.w *= fgr;
            *(float4*)(sh_part + c * SS + 4 * gg) = acc;
            __syncthreads();

            float v = 0.0f;
            if (tid < SS) {
                float y = 0.0f;
                #pragma unroll
                for (int cc = 0; cc < 8; ++cc) y += sh_part[cc * SS + tid];
                v = y;
                float m = v;
                #pragma unroll
                for (int off = 32; off >= 1; off >>= 1)
                    m = fmaxf(m, __shfl_xor(m, off, 64));
                if ((tid & 63) == 0) sh_red[tid >> 6] = m;
            }
            __syncthreads();
            if (tid < SS) {
                const float mm = fmaxf(fmaxf(sh_red[0], sh_red[1]), 1e-37f);
                const int e = (int)((__float_as_uint(mm) >> 23) & 255u);
                const float inv = __uint_as_float((unsigned)(254 - e) << 23);
                e2acc += (e - 127);
                sh_v[tid] = v * inv;
            }
            #pragma unroll
            for (int j = 0; j < 16; ++j) curm[j] = nxt[j];
            __syncthreads();
        }

        if (tid < SS) {
            float s = sh_v[tid];
            #pragma unroll
            for (int off = 32; off >= 1; off >>= 1)
                s += __shfl_xor(s, off, 64);
            if ((tid & 63) == 0) sh_red[tid >> 6] = s;
        }
        __syncthreads();
        if (tid == 0)
            atomicExch(&dsc[u], LN2F * ((float)e2acc + sscal) +
                                __logf(sh_red[0] + sh_red[1]));
    } else {
        // ---------------- num chain: band matvecs ----------------
        const int u = blockIdx.x - NB;
        const _Float16* Bu = Bd + (size_t)u * QNODES * 201 * BST;
        const int r = tid;
        const bool act = (r < 201);

        if (r < 232) { ab[0][r] = NEGV; ab[1][r] = NEGV; }
        h4 nx1[7], nx2[7];
        float dv[BROW];
        if (act) {
            const h4* s0 = (const h4*)(Bu + (size_t)r * BST);
            #pragma unroll
            for (int t7 = 0; t7 < 7; ++t7) nx1[t7] = s0[t7];
            #pragma unroll
            for (int k = 0; k < BROW; ++k) dv[k] = (float)nx1[k >> 2][k & 3];
            const h4* s1 = (const h4*)(Bu + ((size_t)201 + r) * BST);
            #pragma unroll
            for (int t7 = 0; t7 < 7; ++t7) nx1[t7] = s1[t7];
        }
        __syncthreads();
        if (r == 0) ab[0][QDRX] = 0.0f;    // alpha[0] = 0 (log2), offset QDRX
        __syncthreads();

        int cur = 0;
        for (int nd = 0; nd < QNODES; ++nd) {
            if (nd + 2 < QNODES && act) {
                const h4* src = (const h4*)(Bu + ((size_t)(nd + 2) * 201 + r) * BST);
                #pragma unroll
                for (int t7 = 0; t7 < 7; ++t7) nx2[t7] = src[t7];
            }
            float anew = NEGV;
            if (act) {
                float tr[BROW];
                #pragma unroll
                for (int k = 0; k < BROW; ++k)
                    tr[k] = dv[k] + ab[cur][QDRX + r - k];
                float m = tr[0];
                #pragma unroll
                for (int k = 1; k < BROW; ++k) m = fmaxf(m, tr[k]);
                float s = 0.0f;
                #pragma unroll
                for (int k = 0; k < BROW; ++k)
                    s += __builtin_amdgcn_exp2f(tr[k] - m);
                anew = m + __builtin_amdgcn_logf(s);
            }
            if (act) ab[cur ^ 1][QDRX + r] = anew;
            cur ^= 1;
            __syncthreads();
            if (act) {
                #pragma unroll
                for (int k = 0; k < BROW; ++k) dv[k] = (float)nx1[k >> 2][k & 3];
                #pragma unroll
                for (int t7 = 0; t7 < 7; ++t7) nx1[t7] = nx2[t7];
            }
        }
        if (r == 0)
            atomicExch(&dsc[NB + u], ab[cur][QDRX + num_lens[u]] * LN2F);
    }

    // ---------------- fused finalize: last chain block ----------------
    __threadfence();
    if (tid == 0) sfl = ((atomicAdd(ctr, 1u) & 31u) == 31u);
    __syncthreads();
    if (!sfl) return;
    __threadfence();
    if (tid < 64) {
        float tot_score = 0.0f, tot_frames = 0.0f, all_frames = 0.0f;
        if (tid < NB) {
            const float d = atomicAdd(&dsc[tid], 0.0f);       // coherent read
            const float n = atomicAdd(&dsc[NB + tid], 0.0f);
            const float tot = n - d;
            const int nf = sup[tid * 3 + 2];
            const bool fin = isfinite(tot) && (tot > 0.5f * NEGV);
            tot_score  = fin ? tot : 0.0f;
            tot_frames = fin ? (float)nf : 0.0f;
            all_frames = (float)nf;
        }
        #pragma unroll
        for (int off = 32; off >= 1; off >>= 1) {
            tot_score  += __shfl_xor(tot_score, off, 64);
            tot_frames += __shfl_xor(tot_frames, off, 64);
            all_frames += __shfl_xor(all_frames, off, 64);
        }
        if (tid == 0) {
            out[0] = tot_score;
            out[1] = tot_frames;
            out[2] = all_frames;
        }
    }
}

// ======================= Finalize (fallback path only) ======================
__global__ void mmi_finalize(const float* __restrict__ sc,
                             const int* __restrict__ sup,
                             float* __restrict__ out)
{
    const int tid = threadIdx.x;
    float tot_score = 0.0f, tot_frames = 0.0f, all_frames = 0.0f;
    if (tid < NB) {
        const float tot = sc[NB + tid] - sc[tid];
        const int nf = sup[tid * 3 + 2];
        const bool fin = isfinite(tot) && (tot > 0.5f * NEGV);
        tot_score  = fin ? tot : 0.0f;
        tot_frames = fin ? (float)nf : 0.0f;
        all_frames = (float)nf;
    }
    #pragma unroll
    for (int off = 32; off >= 1; off >>= 1) {
        tot_score  += __shfl_xor(tot_score, off, 64);
        tot_frames += __shfl_xor(tot_frames, off, 64);
        all_frames += __shfl_xor(all_frames, off, 64);
    }
    if (tid == 0) {
        out[0] = tot_score;
        out[1] = tot_frames;
        out[2] = all_frames;
    }
}

// ======================= Fallback (validated round-4 kernel) =================
#define XBF (16 * FF)
__global__ __launch_bounds__(256) void mmi_forward_fb(
    const float* __restrict__ x, const int* __restrict__ sup,
    const float* __restrict__ trans, const int* __restrict__ den_labels,
    const int* __restrict__ num_labels, const int* __restrict__ num_lens,
    float* __restrict__ ws)
{
    const int tid = threadIdx.x;
    if (blockIdx.x < NB) {
        __shared__ float sh_v[SS];
        __shared__ float sh_part[8 * SS];
        __shared__ float sh_red[4];
        __shared__ __align__(16) float xbuf[2][XBF];
        const int n = blockIdx.x, nf = sup[n * 3 + 2];
        const int g = tid & 31, c = tid >> 5;
        float4 e[16];
        #pragma unroll
        for (int j = 0; j < 16; ++j) {
            const float4 t4 = *(const float4*)(trans + (size_t)(16 * c + j) * SS + 4 * g);
            e[j] = make_float4(__expf(t4.x), __expf(t4.y), __expf(t4.z), __expf(t4.w));
        }
        const int lab = (tid < SS) ? den_labels[tid & (SS - 1)] : 0;
        const float* xb = x + (size_t)n * TT * FF;
        {
            const float4* s0 = (const float4*)xb;
            float4 p0 = s0[tid]; float4 p1; if (tid < 104) p1 = s0[256 + tid];
            float4* d0 = (float4*)xbuf[0];
            d0[tid] = p0; if (tid < 104) d0[256 + tid] = p1;
        }
        if (tid < SS) sh_v[tid] = (tid == 0) ? 1.0f : 0.0f;
        float logM = 0.0f, v = 0.0f, pe = 0.0f;
        float4 pf0, pf1;
        __syncthreads();
        for (int t = 0; t < nf; ++t) {
            const int b = t >> 4;
            if (tid < SS) pe = __expf(xbuf[b & 1][(t & 15) * FF + lab]);
            float4 aa[4];
            { const float4* av = (const float4*)(sh_v + 16 * c);
              aa[0] = av[0]; aa[1] = av[1]; aa[2] = av[2]; aa[3] = av[3]; }
            const float* as = (const float*)aa;
            float4 acc = make_float4(0.f, 0.f, 0.f, 0.f);
            #pragma unroll
            for (int j = 0; j < 16; ++j) {
                acc.x = fmaf(as[j], e[j].x, acc.x); acc.y = fmaf(as[j], e[j].y, acc.y);
                acc.z = fmaf(as[j], e[j].z, acc.z); acc.w = fmaf(as[j], e[j].w, acc.w);
            }
            *(float4*)(sh_part + c * SS + 4 * g) = acc;
            if ((t & 15) == 8) {
                const int tn = (b + 1) * 16;
                if (tn < nf) {
                    const float4* s = (const float4*)(xb + (size_t)tn * FF);
                    pf0 = s[tid]; if (tid < 104) pf1 = s[256 + tid];
                }
            }
            __syncthreads();
            const bool rs = ((t & 15) == 15);
            if (tid < SS) {
                float y = 0.0f;
                #pragma unroll
                for (int cc = 0; cc < 8; ++cc) y += sh_part[cc * SS + tid];
                v = y * pe;
                if (rs) {
                    float m = v;
                    #pragma unroll
                    for (int off = 32; off >= 1; off >>= 1)
                        m = fmaxf(m, __shfl_xor(m, off, 64));
                    if ((tid & 63) == 0) sh_red[tid >> 6] = m;
                }
            }
            if (rs) {
                const int tn = (b + 1) * 16;
                if (tn < nf) {
                    float4* dst = (float4*)xbuf[(b + 1) & 1];
                    dst[tid] = pf0; if (tid < 104) dst[256 + tid] = pf1;
                }
                __syncthreads();
                if (tid < SS) {
                    float mm = fmaxf(fmaxf(sh_red[0], sh_red[1]), 1e-37f);
                    v *= (1.0f / mm); logM += __logf(mm);
                }
            }
            if (tid < SS) sh_v[tid] = v;
            __syncthreads();
        }
        if (tid < SS) {
            float ssum = v;
            #pragma unroll
            for (int off = 32; off >= 1; off >>= 1) ssum += __shfl_xor(ssum, off, 64);
            if ((tid & 63) == 0) sh_red[2 + (tid >> 6)] = ssum;
        }
        __syncthreads();
        if (tid == 0) ws[n] = logM + __logf(sh_red[2] + sh_red[3]);
    } else {
        const int w = tid >> 6, l = tid & 63;
        const int n = (blockIdx.x - NB) * 4 + w;
        const int nf = sup[n * 3 + 2];
        const float* xb = x + (size_t)n * TT * FF;
        const int* nl = num_labels + n * LL;
        int li[4];
        #pragma unroll
        for (int k = 0; k < 4; ++k) li[k] = nl[min(4 * l + k, LL - 1)];
        float a4[4] = {NEGV, NEGV, NEGV, NEGV};
        float ea[4], eb[4];
        #pragma unroll
        for (int k = 0; k < 4; ++k) ea[k] = xb[li[k]];
        { const float* xr = xb + (size_t)min(1, nf - 1) * FF;
          #pragma unroll
          for (int k = 0; k < 4; ++k) eb[k] = xr[li[k]]; }
        auto step = [&](float (&ee)[4], int t) {
            float left = __shfl_up(a4[3], 1, 64);
            if (l == 0) left = (t == 0) ? 0.0f : NEGV;
            float prev = left;
            #pragma unroll
            for (int k = 0; k < 4; ++k) {
                const float a = a4[k], b = prev;
                const float mx = fmaxf(a, b), mn = fminf(a, b);
                const float nv = mx + __logf(1.0f + __expf(mn - mx)) + ee[k];
                prev = a4[k]; a4[k] = nv;
            }
            const int t2 = min(t + 2, nf - 1);
            const float* xr = xb + (size_t)t2 * FF;
            #pragma unroll
            for (int k = 0; k < 4; ++k) ee[k] = xr[li[k]];
        };
        int t = 0;
        while (t < nf) { step(ea, t); ++t; if (t >= nf) break; step(eb, t); ++t; }
        const int idx = num_lens[n] - 1;
        if ((idx >> 2) == l) {
            const int kk = idx & 3;
            float vv = (kk == 0) ? a4[0] : (kk == 1) ? a4[1] : (kk == 2) ? a4[2] : a4[3];
            ws[NB + n] = vv;
        }
    }
}

extern "C" void kernel_launch(void* const* d_in, const int* in_sizes, int n_in,
                              void* d_out, int out_size, void* d_ws, size_t ws_size,
                              hipStream_t stream) {
    const float* x          = (const float*)d_in[0];
    const int*   sup        = (const int*)d_in[1];
    const float* trans      = (const float*)d_in[2];
    const int*   den_labels = (const int*)d_in[3];
    const int*   num_labels = (const int*)d_in[4];
    const int*   num_lens   = (const int*)d_in[5];
    float* out = (float*)d_out;

    const size_t PBYTES = (size_t)NB * DNODES * 32768;              // 8,388,608
    const size_t BBYTES = (size_t)NB * QNODES * 201 * BST * 2;      // 5,763,072
    const size_t SCB    = (size_t)NB * DNODES * 4 * sizeof(float);  // 16,384
    const size_t SOFF   = PBYTES + BBYTES;
    const size_t DOFF   = SOFF + SCB;              // dsc (64 floats)
    const size_t COFF   = DOFF + 256;              // counter
    const size_t NEEDED = COFF + 256;

    if (ws_size >= NEEDED) {
        unsigned*  Pout    = (unsigned*)d_ws;
        _Float16*  Bd      = (_Float16*)((char*)d_ws + PBYTES);
        float*     scales4 = (float*)((char*)d_ws + SOFF);
        float*     dsc     = (float*)((char*)d_ws + DOFF);
        unsigned*  ctr     = (unsigned*)((char*)d_ws + COFF);
        mmi_nodes<<<dim3(NB * DNODES + NB * QNODES), dim3(256), 0, stream>>>(
            x, sup, trans, den_labels, num_labels, Pout, scales4, Bd);
        mmi_chain<<<dim3(2 * NB), dim3(256), 0, stream>>>(
            (const unsigned short*)d_ws, Bd, scales4, num_lens, sup,
            dsc, ctr, out);
    } else {
        float* ws = (float*)d_ws;
        mmi_forward_fb<<<dim3(20), dim3(256), 0, stream>>>(
            x, sup, trans, den_labels, num_labels, num_lens, ws);
        mmi_finalize<<<dim3(1), dim3(64), 0, stream>>>(ws, sup, out);
    }
}